// Round 4
// baseline (359.718 us; speedup 1.0000x reference)
//
#include <hip/hip_runtime.h>
#include <math.h>

#define NMAT   16384
#define CHEB_A 0.08
#define CHEB_B 7.0
#define DDEG   29            // Chebyshev degree (odd); truncation tail ~5e-4 on [a,b]
#define NCOEF  (DDEG + 1)
#define NITER  ((DDEG - 1) / 2)   // Clenshaw pair-iterations
#define NLOGBLK 2048         // k_logsum blocks
#define NWAVES (NLOGBLK * 4) // 8192 waves -> exactly 2 matrices per wave

// ws float layout
#define WS_GQ    0
#define WS_GSQ   1024
#define WS_C     2112
#define WS_CT    3136

// d_out float scratch layout (consumed before final kernel overwrites):
#define OUT_PA   0          // 256*1024  (stage-1 partial sums of X)
#define OUT_PL   262144     // 2048*1024 (stage-3 partial sums of log)
#define OUT_PL2  2359296    // 32*1024

typedef __attribute__((ext_vector_type(8)))  short short8;   // 8 bf16 (4 VGPRs)
typedef __attribute__((ext_vector_type(16))) float f32x16;   // MFMA 32x32 C/D
typedef __attribute__((ext_vector_type(2)))  float f32x2;
typedef __attribute__((ext_vector_type(2)))  __bf16 bf16x2;

union FB { short8 v; unsigned int w[4]; };
union FV { f32x16 v; f32x2 p[8]; };   // packed-pair view (all indexing unrolled-const)

// round-half-up f32->bf16, pack pair into one dword (lo=a, hi=b). Setup-path only
// (keeps the Gq hi/lo split exactly consistent with rhi()).
__device__ __forceinline__ unsigned int pk2(float a, float b) {
    unsigned int au = __float_as_uint(a) + 0x8000u;
    unsigned int bu = __float_as_uint(b) + 0x8000u;
    return __builtin_amdgcn_perm(bu, au, 0x07060302u);
}
__device__ __forceinline__ float rhi(float x) {   // bf16-rounded value as float
    return __uint_as_float((__float_as_uint(x) + 0x8000u) & 0xffff0000u);
}

// hot-path pack: RNE pack of 2 f32 -> 2 bf16 (lo=a, hi=b), compiler-emitted
// (vector fptrunc; gfx950 backend selects v_cvt_pk_bf16_f32 itself).
__device__ __forceinline__ unsigned int cvt2(float a, float b) {
    f32x2 s; s.x = a; s.y = b;
    bf16x2 t = __builtin_convertvector(s, bf16x2);
    unsigned int r;
    __builtin_memcpy(&r, &t, 4);
    return r;
}

// D (C/D layout fp32) -> two B-operand k-half fragments, pure in-register.
// C/D layout is column-owned (lane holds col=lane&31, rows (r&3)+8*(r>>2)+4h);
// B layout is also column-owned (lane holds col, k=8h+e). The only data motion
// needed is a half-wave exchange lane <-> lane^32: v_permlane32_swap_b32.
template <bool HALF>
__device__ __forceinline__ void toB(const f32x16& d, FB& b1, FB& b2) {
    unsigned int p[8];
#pragma unroll
    for (int g = 0; g < 8; ++g) {
        float s0 = HALF ? 0.5f * d[2 * g]     : d[2 * g];
        float s1 = HALF ? 0.5f * d[2 * g + 1] : d[2 * g + 1];
        p[g] = cvt2(s0, s1);
    }
    auto r02 = __builtin_amdgcn_permlane32_swap(p[0], p[2], false, false);
    auto r13 = __builtin_amdgcn_permlane32_swap(p[1], p[3], false, false);
    auto r46 = __builtin_amdgcn_permlane32_swap(p[4], p[6], false, false);
    auto r57 = __builtin_amdgcn_permlane32_swap(p[5], p[7], false, false);
    b1.w[0] = r02[0]; b1.w[1] = r13[0]; b1.w[2] = r02[1]; b1.w[3] = r13[1];
    b2.w[0] = r46[0]; b2.w[1] = r57[0]; b2.w[2] = r46[1]; b2.w[3] = r57[1];
}

#define MFMA(a, b, c) __builtin_amdgcn_mfma_f32_32x32x16_bf16((a), (b), (c), 0, 0, 0)

// ---------------- block-level 32x32 matmul on LDS (row-major), 256 threads ----------------
__device__ __forceinline__ void mm32(const float* A, const float* B, float* D, int t) {
    int i = t >> 3, j0 = (t & 7) * 4;
    float a[32];
#pragma unroll
    for (int q = 0; q < 8; ++q) {
        float4 v = *(const float4*)&A[i * 32 + q * 4];
        a[4 * q] = v.x; a[4 * q + 1] = v.y; a[4 * q + 2] = v.z; a[4 * q + 3] = v.w;
    }
    float ax = 0.f, ay = 0.f, az = 0.f, aw = 0.f;
#pragma unroll
    for (int k = 0; k < 32; ++k) {
        float4 bv = *(const float4*)&B[k * 32 + j0];
        ax += a[k] * bv.x; ay += a[k] * bv.y; az += a[k] * bv.z; aw += a[k] * bv.w;
    }
    float4 r = { ax, ay, az, aw };
    *(float4*)&D[i * 32 + j0] = r;
}

// ---------------- K1: partial sums (256 blocks x 64 matrices) ----------------
__global__ __launch_bounds__(256) void k_psum(const float4* __restrict__ X4,
                                              float4* __restrict__ pA4) {
    int b = blockIdx.x, t = threadIdx.x;
    float4 acc = { 0.f, 0.f, 0.f, 0.f };
    for (int r = 0; r < 64; ++r) {
        float4 v = X4[(size_t)(b * 64 + r) * 256 + t];
        acc.x += v.x; acc.y += v.y; acc.z += v.z; acc.w += v.w;
    }
    pA4[b * 256 + t] = acc;
}

// ---------------- K2: finalize G, G^{1/2}, G^{-1/2} ----------------
__global__ __launch_bounds__(256) void k_setup(const float4* __restrict__ pA4,
                                               float* __restrict__ ws) {
    __shared__ alignas(16) float sG[1024], sE[1024], sPa[1024], sPb[1024], sS1[1024], sS2[1024];
    __shared__ float sc[2];
    int t = threadIdx.x;
    float4 acc = { 0.f, 0.f, 0.f, 0.f };
    for (int b = 0; b < 256; ++b) {
        float4 v = pA4[b * 256 + t];
        acc.x += v.x; acc.y += v.y; acc.z += v.z; acc.w += v.w;
    }
    const float invM = 1.0f / (float)NMAT;
    sG[4 * t + 0] = acc.x * invM; sG[4 * t + 1] = acc.y * invM;
    sG[4 * t + 2] = acc.z * invM; sG[4 * t + 3] = acc.w * invM;
    __syncthreads();
    if (t == 0) { float s = 0.f; for (int d = 0; d < 32; ++d) s += sG[d * 33]; sc[0] = s / 32.0f; }
    __syncthreads();
    float c = sc[0];
    int i = t >> 3, j0 = (t & 7) * 4;
#pragma unroll
    for (int q = 0; q < 4; ++q) {
        int e = i * 32 + j0 + q;
        sE[e] = sG[e] / c - ((i == j0 + q) ? 1.f : 0.f);
    }
    __syncthreads();
    const float alp[9] = { 1.f, 0.5f, -0.125f, 0.0625f, -0.0390625f, 0.02734375f,
                           -0.0205078125f, 0.01611328125f, -0.013092041015625f };
    const float bet[9] = { 1.f, -0.5f, 0.375f, -0.3125f, 0.2734375f, -0.24609375f,
                           0.2255859375f, -0.20947265625f, 0.196380615234375f };
#pragma unroll
    for (int q = 0; q < 4; ++q) {
        int e = i * 32 + j0 + q;
        float d = (i == j0 + q) ? 1.f : 0.f;
        sS1[e] = d + alp[1] * sE[e];
        sS2[e] = d + bet[1] * sE[e];
        sPa[e] = sE[e];
    }
    __syncthreads();
    {
        float* P = sPa; float* Pn = sPb;
        for (int k = 2; k <= 8; ++k) {
            mm32(P, sE, Pn, t);
            __syncthreads();
#pragma unroll
            for (int q = 0; q < 4; ++q) {
                int e = i * 32 + j0 + q;
                sS1[e] += alp[k] * Pn[e];
                sS2[e] += bet[k] * Pn[e];
            }
            float* tmp = P; P = Pn; Pn = tmp;
            __syncthreads();
        }
    }
    float rc = sqrtf(c);
#pragma unroll
    for (int q = 0; q < 4; ++q) {
        int e = i * 32 + j0 + q;
        ws[WS_GSQ + e] = rc * sS1[e];
        ws[WS_GQ + e]  = sS2[e] / rc;
    }
}

// ---------------- K3: sum of matrix logs, MFMA Clenshaw ----------------
__global__ __launch_bounds__(256, 4) void k_logsum(const float* __restrict__ Xg,
                                                   const float* __restrict__ ws,
                                                   float* __restrict__ pL) {
    __shared__ float sLacc[1024];
    __shared__ float scheb[NCOEF];
    int t = threadIdx.x;
    for (int e = t; e < 1024; e += 256) sLacc[e] = 0.f;
    if (t < NCOEF) {
        // closed-form Chebyshev coeffs of log on [a,b]
        float alpha = 0.5f * (float)(CHEB_A + CHEB_B);
        float beta  = 0.5f * (float)(CHEB_B - CHEB_A);
        float dd = beta / alpha, s = sqrtf(1.f - dd * dd), tt = dd / (1.f + s);
        float v;
        if (t == 0) v = 2.f * (logf(alpha) + logf(0.5f * (1.f + s)));
        else        v = 2.f * ((t & 1) ? 1.f : -1.f) * exp2f((float)t * log2f(tt)) / (float)t;
        scheb[t] = v;
    }
    const int wv = t >> 6, lane = t & 63, h = lane >> 5, col = lane & 31;

    // diagonal mask in C/D layout: row(reg)=(reg&3)+8*(reg>>2)+4h == col
    int hasd = (((col >> 2) & 1) == h);
    int dreg = 4 * (col >> 3) + (col & 3);
    FV dm;
#pragma unroll
    for (int r = 0; r < 16; ++r) dm.v[r] = (hasd && r == dreg) ? 1.f : 0.f;

    // Gq fragments (symmetric; same regs serve as A- and B-operand), hi/lo split
    const float* Gqp = ws + WS_GQ + col * 32 + 8 * h;
    float4 ga = *(const float4*)(Gqp);
    float4 gb = *(const float4*)(Gqp + 4);
    float4 gc = *(const float4*)(Gqp + 16);
    float4 gd = *(const float4*)(Gqp + 20);
    FB GqH1, GqH2, GqL1, GqL2;
    GqH1.w[0] = pk2(ga.x, ga.y); GqH1.w[1] = pk2(ga.z, ga.w);
    GqH1.w[2] = pk2(gb.x, gb.y); GqH1.w[3] = pk2(gb.z, gb.w);
    GqH2.w[0] = pk2(gc.x, gc.y); GqH2.w[1] = pk2(gc.z, gc.w);
    GqH2.w[2] = pk2(gd.x, gd.y); GqH2.w[3] = pk2(gd.z, gd.w);
    GqL1.w[0] = pk2(ga.x - rhi(ga.x), ga.y - rhi(ga.y));
    GqL1.w[1] = pk2(ga.z - rhi(ga.z), ga.w - rhi(ga.w));
    GqL1.w[2] = pk2(gb.x - rhi(gb.x), gb.y - rhi(gb.y));
    GqL1.w[3] = pk2(gb.z - rhi(gb.z), gb.w - rhi(gb.w));
    GqL2.w[0] = pk2(gc.x - rhi(gc.x), gc.y - rhi(gc.y));
    GqL2.w[1] = pk2(gc.z - rhi(gc.z), gc.w - rhi(gc.w));
    GqL2.w[2] = pk2(gd.x - rhi(gd.x), gd.y - rhi(gd.y));
    GqL2.w[3] = pk2(gd.z - rhi(gd.z), gd.w - rhi(gd.w));
    __syncthreads();   // scheb + sLacc ready

    FV Facc;
#pragma unroll
    for (int r = 0; r < 16; ++r) Facc.v[r] = 0.f;
    const float m2v = 2.0f / (float)(CHEB_B - CHEB_A);
    const float shv = (float)((CHEB_A + CHEB_B) / (CHEB_B - CHEB_A));
    const float tm = 2.f * m2v, tsh = -2.f * shv;
    const float cDv = scheb[DDEG], c0h = 0.5f * scheb[0];
    const f32x2 tmv = { tm, tm };

    // constants hoisted out of the m-loop: cD*I (Clenshaw seed) and tsh*I
    FV cDdm, tshdm;
#pragma unroll
    for (int r = 0; r < 8; ++r) { cDdm.p[r] = cDv * dm.p[r]; tshdm.p[r] = tsh * dm.p[r]; }
    FB CDB1, CDB2;
    toB<false>(cDdm.v, CDB1, CDB2);

    for (int m = blockIdx.x * 4 + wv; m < NMAT; m += NWAVES) {
        const float* Xm = Xg + (size_t)m * 1024 + col * 32 + 8 * h;
        float4 xa = *(const float4*)(Xm);
        float4 xb = *(const float4*)(Xm + 4);
        float4 xc = *(const float4*)(Xm + 16);
        float4 xd = *(const float4*)(Xm + 20);
        FB AX1, AX2;
        AX1.w[0] = cvt2(xa.x, xa.y); AX1.w[1] = cvt2(xa.z, xa.w);
        AX1.w[2] = cvt2(xb.x, xb.y); AX1.w[3] = cvt2(xb.z, xb.w);
        AX2.w[0] = cvt2(xc.x, xc.y); AX2.w[1] = cvt2(xc.z, xc.w);
        AX2.w[2] = cvt2(xd.x, xd.y); AX2.w[3] = cvt2(xd.z, xd.w);

        // U = X * Gq   (X symmetric -> direct A-frags; Gq split hi+lo)
        FV U;
#pragma unroll
        for (int r = 0; r < 16; ++r) U.v[r] = 0.f;
        U.v = MFMA(AX2.v, GqL2.v, U.v); U.v = MFMA(AX1.v, GqL1.v, U.v);
        U.v = MFMA(AX2.v, GqH2.v, U.v); U.v = MFMA(AX1.v, GqH1.v, U.v);
        FB B1, B2;
        toB<false>(U.v, B1, B2);
        // S = Gq * U
        FV S;
#pragma unroll
        for (int r = 0; r < 16; ++r) S.v[r] = 0.f;
        S.v = MFMA(GqL2.v, B2.v, S.v); S.v = MFMA(GqL1.v, B1.v, S.v);
        S.v = MFMA(GqH2.v, B2.v, S.v); S.v = MFMA(GqH1.v, B1.v, S.v);
        // 2*Shat = tm*S + tsh*I  -> A-operand frags (symmetric)
        FV T;
#pragma unroll
        for (int r = 0; r < 8; ++r)
            T.p[r] = __builtin_elementwise_fma(tmv, S.p[r], tshdm.p[r]);
        FB A1, A2;
        toB<false>(T.v, A1, A2);

        // Clenshaw: b_k = c_k I - b_{k+2} + (2Shat)*b_{k+1}
        FV X0, X1;
        X1.v = cDdm.v;
#pragma unroll
        for (int r = 0; r < 16; ++r) X0.v[r] = 0.f;
        B1 = CDB1; B2 = CDB2;
        for (int it = 0; it < NITER; ++it) {
            float ka = scheb[DDEG - 1 - 2 * it];
            float kb = scheb[DDEG - 2 - 2 * it];
            const f32x2 kav = { ka, ka }, kbv = { kb, kb };
#pragma unroll
            for (int r = 0; r < 8; ++r)
                X0.p[r] = __builtin_elementwise_fma(kav, dm.p[r], -X0.p[r]);
            X0.v = MFMA(A2.v, B2.v, X0.v); X0.v = MFMA(A1.v, B1.v, X0.v);
            toB<false>(X0.v, B1, B2);
#pragma unroll
            for (int r = 0; r < 8; ++r)
                X1.p[r] = __builtin_elementwise_fma(kbv, dm.p[r], -X1.p[r]);
            X1.v = MFMA(A2.v, B2.v, X1.v); X1.v = MFMA(A1.v, B1.v, X1.v);
            if (it < NITER - 1) toB<false>(X1.v, B1, B2);
            else                toB<true>(X1.v, B1, B2);   // 0.5*b_1
        }
        // f = 0.5*c0 I - b_2 + (2Shat)*(0.5 b_1)
        {
            const f32x2 c0v = { c0h, c0h };
#pragma unroll
            for (int r = 0; r < 8; ++r)
                X0.p[r] = __builtin_elementwise_fma(c0v, dm.p[r], -X0.p[r]);
        }
        X0.v = MFMA(A2.v, B2.v, X0.v); X0.v = MFMA(A1.v, B1.v, X0.v);
#pragma unroll
        for (int r = 0; r < 8; ++r) Facc.p[r] += X0.p[r];
    }
#pragma unroll
    for (int r = 0; r < 16; ++r) {
        int row = (r & 3) + 8 * (r >> 2) + 4 * h;
        atomicAdd(&sLacc[row * 32 + col], Facc.v[r]);
    }
    __syncthreads();
    float4 v = *(float4*)&sLacc[4 * t];
    ((float4*)pL)[(size_t)blockIdx.x * 256 + t] = v;
}

// ---------------- K3b: reduce 2048 partials -> 32 ----------------
__global__ __launch_bounds__(256) void k_red32(const float4* __restrict__ pL4,
                                               float4* __restrict__ pL24) {
    int b = blockIdx.x, t = threadIdx.x;
    float4 acc = { 0.f, 0.f, 0.f, 0.f };
    for (int r = 0; r < 64; ++r) {
        float4 v = pL4[(size_t)(b * 64 + r) * 256 + t];
        acc.x += v.x; acc.y += v.y; acc.z += v.z; acc.w += v.w;
    }
    pL24[b * 256 + t] = acc;
}

// ---------------- K4: L -> expL -> Gn -> Gn^{-1/2}; W^{1/2}; C = Wsq*Gn_isq ----------------
__global__ __launch_bounds__(256) void k_final(const float4* __restrict__ pL24,
                                               const float* __restrict__ Wg,
                                               float* __restrict__ ws) {
    __shared__ alignas(16) float B0[1024], B1[1024], B2[1024], B3[1024], B4[1024], B5[1024], B6[1024];
    __shared__ float sc[4];
    int t = threadIdx.x;
    int i = t >> 3, j0 = (t & 7) * 4;
    if (t == 0) { sc[2] = 0.f; }
    float4 acc = { 0.f, 0.f, 0.f, 0.f };
    for (int b = 0; b < 32; ++b) {
        float4 v = pL24[b * 256 + t];
        acc.x += v.x; acc.y += v.y; acc.z += v.z; acc.w += v.w;
    }
    const float invM = 1.0f / (float)NMAT;
    B0[4 * t + 0] = acc.x * invM; B0[4 * t + 1] = acc.y * invM;
    B0[4 * t + 2] = acc.z * invM; B0[4 * t + 3] = acc.w * invM;
    __syncthreads();
    if (t == 0) { float s = 0.f; for (int d = 0; d < 32; ++d) s += B0[d * 33]; sc[0] = s / 32.0f; }
    __syncthreads();
    float s0 = sc[0];
#pragma unroll
    for (int q = 0; q < 4; ++q) {
        int e = i * 32 + j0 + q;
        B1[e] = B0[e] - ((i == j0 + q) ? s0 : 0.f);   // L0
    }
    __syncthreads();
#pragma unroll
    for (int q = 0; q < 4; ++q) {
        int e = i * 32 + j0 + q;
        float d = (i == j0 + q) ? 1.f : 0.f;
        B2[e] = B1[e];
        B4[e] = d + B1[e];
    }
    __syncthreads();
    {
        float* P = B2; float* Pn = B3;
        for (int k = 2; k <= 12; ++k) {
            mm32(P, B1, Pn, t);
            __syncthreads();
            float invk = 1.0f / (float)k;
#pragma unroll
            for (int q = 0; q < 4; ++q) {
                int e = i * 32 + j0 + q;
                Pn[e] *= invk;
                B4[e] += Pn[e];
            }
            float* tmp = P; P = Pn; Pn = tmp;
            __syncthreads();
        }
    }
    float es = expf(s0);
#pragma unroll
    for (int q = 0; q < 4; ++q) B4[i * 32 + j0 + q] *= es;   // expL
    __syncthreads();
    for (int e = t; e < 1024; e += 256) B5[e] = ws[WS_GSQ + e];
    __syncthreads();
    mm32(B5, B4, B6, t); __syncthreads();
    mm32(B6, B5, B0, t); __syncthreads();                    // Gn in B0
    if (t == 0) { float s = 0.f; for (int d = 0; d < 32; ++d) s += B0[d * 33]; sc[1] = s / 32.0f; }
    __syncthreads();
    float c2 = sc[1];
#pragma unroll
    for (int q = 0; q < 4; ++q) {
        int e = i * 32 + j0 + q;
        B2[e] = B0[e] / c2;
        B3[e] = (i == j0 + q) ? 1.f : 0.f;
    }
    __syncthreads();
    {   // coupled NS for Gn/c2: Z->rsqrt
        float* Y = B2; float* Z = B3; float* T = B6; float* Ya = B1; float* Zb = B4;
        for (int it = 0; it < 8; ++it) {
            mm32(Z, Y, T, t); __syncthreads();
#pragma unroll
            for (int q = 0; q < 4; ++q) {
                int e = i * 32 + j0 + q;
                T[e] = 0.5f * (3.f * ((i == j0 + q) ? 1.f : 0.f) - T[e]);
            }
            __syncthreads();
            mm32(Y, T, Ya, t); mm32(T, Z, Zb, t); __syncthreads();
            float* tmp = Y; Y = Ya; Ya = tmp;
            tmp = Z; Z = Zb; Zb = tmp;
        }
        float rc2 = rsqrtf(c2);
#pragma unroll
        for (int q = 0; q < 4; ++q) {
            int e = i * 32 + j0 + q;
            B5[e] = Z[e] * rc2;      // Gn^{-1/2}
        }
    }
    __syncthreads();
    for (int e = t; e < 1024; e += 256) B0[e] = Wg[e];
    __syncthreads();
    {
        float ls = 0.f;
#pragma unroll
        for (int q = 0; q < 4; ++q) { float w = B0[i * 32 + j0 + q]; ls += w * w; }
        atomicAdd(&sc[2], ls);
    }
    __syncthreads();
    float c3 = sqrtf(sc[2]);
#pragma unroll
    for (int q = 0; q < 4; ++q) {
        int e = i * 32 + j0 + q;
        B2[e] = B0[e] / c3;
        B3[e] = (i == j0 + q) ? 1.f : 0.f;
    }
    __syncthreads();
    {
        float* Y = B2; float* Z = B3; float* T = B6; float* Ya = B1; float* Zb = B4;
        for (int it = 0; it < 15; ++it) {
            mm32(Z, Y, T, t); __syncthreads();
#pragma unroll
            for (int q = 0; q < 4; ++q) {
                int e = i * 32 + j0 + q;
                T[e] = 0.5f * (3.f * ((i == j0 + q) ? 1.f : 0.f) - T[e]);
            }
            __syncthreads();
            mm32(Y, T, Ya, t); mm32(T, Z, Zb, t); __syncthreads();
            float* tmp = Y; Y = Ya; Ya = tmp;
            tmp = Z; Z = Zb; Zb = tmp;
        }
        float rc3 = sqrtf(c3);
#pragma unroll
        for (int q = 0; q < 4; ++q) {
            int e = i * 32 + j0 + q;
            B0[e] = Y[e] * rc3;      // W^{1/2}
        }
    }
    __syncthreads();
    mm32(B0, B5, B6, t); __syncthreads();   // C = Wsq * Gn_isq
#pragma unroll
    for (int q = 0; q < 4; ++q) {
        int e = i * 32 + j0 + q;
        ws[WS_C + e] = B6[e];
        ws[WS_CT + (j0 + q) * 32 + i] = B6[e];
    }
}

// ---------------- K5: out = C * X * C^T ----------------
__global__ __launch_bounds__(256) void k_out(const float* __restrict__ Xg,
                                             const float* __restrict__ ws,
                                             float* __restrict__ Og) {
    __shared__ alignas(16) float sCT[1024];
    __shared__ alignas(16) float sX[1024];
    __shared__ alignas(16) float sTt[33 * 32];
    int t = threadIdx.x;
    int i = t >> 3, j0 = (t & 7) * 4;
    for (int e = t; e < 1024; e += 256) sCT[e] = ws[WS_CT + e];
    __syncthreads();
    for (int r = 0; r < 8; ++r) {
        int m = blockIdx.x * 8 + r;
        const float4* Xm4 = (const float4*)(Xg + (size_t)m * 1024);
        *(float4*)&sX[4 * t] = Xm4[t];
        __syncthreads();
        float ax = 0.f, ay = 0.f, az = 0.f, aw = 0.f;
#pragma unroll
        for (int k = 0; k < 32; ++k) {
            float cv = sCT[k * 32 + i];
            float4 xv = *(const float4*)&sX[k * 32 + j0];
            ax += cv * xv.x; ay += cv * xv.y; az += cv * xv.z; aw += cv * xv.w;
        }
        sTt[(j0 + 0) * 33 + i] = ax; sTt[(j0 + 1) * 33 + i] = ay;
        sTt[(j0 + 2) * 33 + i] = az; sTt[(j0 + 3) * 33 + i] = aw;
        __syncthreads();
        ax = ay = az = aw = 0.f;
#pragma unroll
        for (int k = 0; k < 32; ++k) {
            float tv = sTt[k * 33 + i];
            float4 cv = *(const float4*)&sCT[k * 32 + j0];
            ax += tv * cv.x; ay += tv * cv.y; az += tv * cv.z; aw += tv * cv.w;
        }
        float4 r4 = { ax, ay, az, aw };
        *(float4*)&Og[(size_t)m * 1024 + i * 32 + j0] = r4;
        __syncthreads();
    }
}

extern "C" void kernel_launch(void* const* d_in, const int* in_sizes, int n_in,
                              void* d_out, int out_size, void* d_ws, size_t ws_size,
                              hipStream_t stream) {
    const float* X = (const float*)d_in[0];
    const float* W = (const float*)d_in[1];
    float* out = (float*)d_out;
    float* ws  = (float*)d_ws;
    float* pA  = out + OUT_PA;
    float* pL  = out + OUT_PL;
    float* pL2 = out + OUT_PL2;

    hipLaunchKernelGGL(k_psum,   dim3(256),     dim3(256), 0, stream, (const float4*)X, (float4*)pA);
    hipLaunchKernelGGL(k_setup,  dim3(1),       dim3(256), 0, stream, (const float4*)pA, ws);
    hipLaunchKernelGGL(k_logsum, dim3(NLOGBLK), dim3(256), 0, stream, X, ws, pL);
    hipLaunchKernelGGL(k_red32,  dim3(32),      dim3(256), 0, stream, (const float4*)pL, (float4*)pL2);
    hipLaunchKernelGGL(k_final,  dim3(1),       dim3(256), 0, stream, (const float4*)pL2, W, ws);
    hipLaunchKernelGGL(k_out,    dim3(2048),    dim3(256), 0, stream, X, ws, out);
}

// Round 5
// 338.914 us; speedup vs baseline: 1.0614x; 1.0614x over previous
//
#include <hip/hip_runtime.h>
#include <math.h>

#define NMAT   16384
#define CHEB_A 0.08
#define CHEB_B 7.0
#define DDEG   29            // Chebyshev degree (odd); truncation tail ~5e-4 on [a,b]
#define NCOEF  (DDEG + 1)
#define NITER  ((DDEG - 1) / 2)   // Clenshaw pair-iterations
#define NLOGBLK 2048         // k_logsum blocks
#define NWAVES (NLOGBLK * 4) // 8192 waves -> exactly 2 matrices per wave

// ws float layout
#define WS_GQ    0
#define WS_GSQ   1024
#define WS_C     2112
#define WS_CT    3136

// d_out float scratch layout (consumed before final kernel overwrites):
#define OUT_PA   0          // 256*1024  (stage-1 partial sums of X)
#define OUT_PL   262144     // 2048*1024 (stage-3 partial sums of log)
#define OUT_PL2  2359296    // 32*1024

typedef __attribute__((ext_vector_type(8)))  short short8;   // 8 bf16 (4 VGPRs)
typedef __attribute__((ext_vector_type(16))) float f32x16;   // MFMA 32x32 C/D
typedef __attribute__((ext_vector_type(2)))  float f32x2;
typedef __attribute__((ext_vector_type(2)))  __bf16 bf16x2;

union FB { short8 v; unsigned int w[4]; };

// round-half-up f32->bf16, pack pair into one dword (lo=a, hi=b). Setup-path only
// (keeps the Gq hi/lo split exactly consistent with rhi()).
__device__ __forceinline__ unsigned int pk2(float a, float b) {
    unsigned int au = __float_as_uint(a) + 0x8000u;
    unsigned int bu = __float_as_uint(b) + 0x8000u;
    return __builtin_amdgcn_perm(bu, au, 0x07060302u);
}
__device__ __forceinline__ float rhi(float x) {   // bf16-rounded value as float
    return __uint_as_float((__float_as_uint(x) + 0x8000u) & 0xffff0000u);
}

// hot-path pack: RNE pack of 2 f32 -> 2 bf16 (lo=a, hi=b), compiler-emitted
// (vector fptrunc; gfx950 backend selects v_cvt_pk_bf16_f32 itself).
__device__ __forceinline__ unsigned int cvt2(float a, float b) {
    f32x2 s; s.x = a; s.y = b;
    bf16x2 t = __builtin_convertvector(s, bf16x2);
    unsigned int r;
    __builtin_memcpy(&r, &t, 4);
    return r;
}

// D (C/D layout fp32) -> two B-operand k-half fragments, pure in-register.
// C/D layout is column-owned (lane holds col=lane&31, rows (r&3)+8*(r>>2)+4h);
// B layout is also column-owned (lane holds col, k=8h+e). The only data motion
// needed is a half-wave exchange lane <-> lane^32: v_permlane32_swap_b32.
template <bool HALF>
__device__ __forceinline__ void toB(const f32x16& d, FB& b1, FB& b2) {
    unsigned int p[8];
#pragma unroll
    for (int g = 0; g < 8; ++g) {
        float s0 = HALF ? 0.5f * d[2 * g]     : d[2 * g];
        float s1 = HALF ? 0.5f * d[2 * g + 1] : d[2 * g + 1];
        p[g] = cvt2(s0, s1);
    }
    auto r02 = __builtin_amdgcn_permlane32_swap(p[0], p[2], false, false);
    auto r13 = __builtin_amdgcn_permlane32_swap(p[1], p[3], false, false);
    auto r46 = __builtin_amdgcn_permlane32_swap(p[4], p[6], false, false);
    auto r57 = __builtin_amdgcn_permlane32_swap(p[5], p[7], false, false);
    b1.w[0] = r02[0]; b1.w[1] = r13[0]; b1.w[2] = r02[1]; b1.w[3] = r13[1];
    b2.w[0] = r46[0]; b2.w[1] = r57[0]; b2.w[2] = r46[1]; b2.w[3] = r57[1];
}

#define MFMA(a, b, c) __builtin_amdgcn_mfma_f32_32x32x16_bf16((a), (b), (c), 0, 0, 0)

// ---------------- block-level 32x32 matmul on LDS (row-major), 256 threads ----------------
__device__ __forceinline__ void mm32(const float* A, const float* B, float* D, int t) {
    int i = t >> 3, j0 = (t & 7) * 4;
    float a[32];
#pragma unroll
    for (int q = 0; q < 8; ++q) {
        float4 v = *(const float4*)&A[i * 32 + q * 4];
        a[4 * q] = v.x; a[4 * q + 1] = v.y; a[4 * q + 2] = v.z; a[4 * q + 3] = v.w;
    }
    float ax = 0.f, ay = 0.f, az = 0.f, aw = 0.f;
#pragma unroll
    for (int k = 0; k < 32; ++k) {
        float4 bv = *(const float4*)&B[k * 32 + j0];
        ax += a[k] * bv.x; ay += a[k] * bv.y; az += a[k] * bv.z; aw += a[k] * bv.w;
    }
    float4 r = { ax, ay, az, aw };
    *(float4*)&D[i * 32 + j0] = r;
}

// ---------------- K1: partial sums (256 blocks x 64 matrices) ----------------
__global__ __launch_bounds__(256) void k_psum(const float4* __restrict__ X4,
                                              float4* __restrict__ pA4) {
    int b = blockIdx.x, t = threadIdx.x;
    float4 acc = { 0.f, 0.f, 0.f, 0.f };
    for (int r = 0; r < 64; ++r) {
        float4 v = X4[(size_t)(b * 64 + r) * 256 + t];
        acc.x += v.x; acc.y += v.y; acc.z += v.z; acc.w += v.w;
    }
    pA4[b * 256 + t] = acc;
}

// ---------------- K2: finalize G, G^{1/2}, G^{-1/2} ----------------
__global__ __launch_bounds__(256) void k_setup(const float4* __restrict__ pA4,
                                               float* __restrict__ ws) {
    __shared__ alignas(16) float sG[1024], sE[1024], sPa[1024], sPb[1024], sS1[1024], sS2[1024];
    __shared__ float sc[2];
    int t = threadIdx.x;
    float4 acc = { 0.f, 0.f, 0.f, 0.f };
    for (int b = 0; b < 256; ++b) {
        float4 v = pA4[b * 256 + t];
        acc.x += v.x; acc.y += v.y; acc.z += v.z; acc.w += v.w;
    }
    const float invM = 1.0f / (float)NMAT;
    sG[4 * t + 0] = acc.x * invM; sG[4 * t + 1] = acc.y * invM;
    sG[4 * t + 2] = acc.z * invM; sG[4 * t + 3] = acc.w * invM;
    __syncthreads();
    if (t == 0) { float s = 0.f; for (int d = 0; d < 32; ++d) s += sG[d * 33]; sc[0] = s / 32.0f; }
    __syncthreads();
    float c = sc[0];
    int i = t >> 3, j0 = (t & 7) * 4;
#pragma unroll
    for (int q = 0; q < 4; ++q) {
        int e = i * 32 + j0 + q;
        sE[e] = sG[e] / c - ((i == j0 + q) ? 1.f : 0.f);
    }
    __syncthreads();
    const float alp[9] = { 1.f, 0.5f, -0.125f, 0.0625f, -0.0390625f, 0.02734375f,
                           -0.0205078125f, 0.01611328125f, -0.013092041015625f };
    const float bet[9] = { 1.f, -0.5f, 0.375f, -0.3125f, 0.2734375f, -0.24609375f,
                           0.2255859375f, -0.20947265625f, 0.196380615234375f };
#pragma unroll
    for (int q = 0; q < 4; ++q) {
        int e = i * 32 + j0 + q;
        float d = (i == j0 + q) ? 1.f : 0.f;
        sS1[e] = d + alp[1] * sE[e];
        sS2[e] = d + bet[1] * sE[e];
        sPa[e] = sE[e];
    }
    __syncthreads();
    {
        float* P = sPa; float* Pn = sPb;
        for (int k = 2; k <= 8; ++k) {
            mm32(P, sE, Pn, t);
            __syncthreads();
#pragma unroll
            for (int q = 0; q < 4; ++q) {
                int e = i * 32 + j0 + q;
                sS1[e] += alp[k] * Pn[e];
                sS2[e] += bet[k] * Pn[e];
            }
            float* tmp = P; P = Pn; Pn = tmp;
            __syncthreads();
        }
    }
    float rc = sqrtf(c);
#pragma unroll
    for (int q = 0; q < 4; ++q) {
        int e = i * 32 + j0 + q;
        ws[WS_GSQ + e] = rc * sS1[e];
        ws[WS_GQ + e]  = sS2[e] / rc;
    }
}

// ---------------- K3: sum of matrix logs, MFMA Clenshaw ----------------
__global__ __launch_bounds__(256, 4) void k_logsum(const float* __restrict__ Xg,
                                                   const float* __restrict__ ws,
                                                   float* __restrict__ pL) {
    __shared__ float sLacc[1024];
    __shared__ float scheb[NCOEF];
    int t = threadIdx.x;
    for (int e = t; e < 1024; e += 256) sLacc[e] = 0.f;
    if (t < NCOEF) {
        // closed-form Chebyshev coeffs of log on [a,b]
        float alpha = 0.5f * (float)(CHEB_A + CHEB_B);
        float beta  = 0.5f * (float)(CHEB_B - CHEB_A);
        float dd = beta / alpha, s = sqrtf(1.f - dd * dd), tt = dd / (1.f + s);
        float v;
        if (t == 0) v = 2.f * (logf(alpha) + logf(0.5f * (1.f + s)));
        else        v = 2.f * ((t & 1) ? 1.f : -1.f) * exp2f((float)t * log2f(tt)) / (float)t;
        scheb[t] = v;
    }
    const int wv = t >> 6, lane = t & 63, h = lane >> 5, col = lane & 31;

    // diagonal mask in C/D layout: row(reg)=(reg&3)+8*(reg>>2)+4h == col
    int hasd = (((col >> 2) & 1) == h);
    int dreg = 4 * (col >> 3) + (col & 3);
    f32x16 dm;
#pragma unroll
    for (int r = 0; r < 16; ++r) dm[r] = (hasd && r == dreg) ? 1.f : 0.f;

    // Gq fragments (symmetric; same regs serve as A- and B-operand), hi/lo split
    const float* Gqp = ws + WS_GQ + col * 32 + 8 * h;
    float4 ga = *(const float4*)(Gqp);
    float4 gb = *(const float4*)(Gqp + 4);
    float4 gc = *(const float4*)(Gqp + 16);
    float4 gd = *(const float4*)(Gqp + 20);
    FB GqH1, GqH2, GqL1, GqL2;
    GqH1.w[0] = pk2(ga.x, ga.y); GqH1.w[1] = pk2(ga.z, ga.w);
    GqH1.w[2] = pk2(gb.x, gb.y); GqH1.w[3] = pk2(gb.z, gb.w);
    GqH2.w[0] = pk2(gc.x, gc.y); GqH2.w[1] = pk2(gc.z, gc.w);
    GqH2.w[2] = pk2(gd.x, gd.y); GqH2.w[3] = pk2(gd.z, gd.w);
    GqL1.w[0] = pk2(ga.x - rhi(ga.x), ga.y - rhi(ga.y));
    GqL1.w[1] = pk2(ga.z - rhi(ga.z), ga.w - rhi(ga.w));
    GqL1.w[2] = pk2(gb.x - rhi(gb.x), gb.y - rhi(gb.y));
    GqL1.w[3] = pk2(gb.z - rhi(gb.z), gb.w - rhi(gb.w));
    GqL2.w[0] = pk2(gc.x - rhi(gc.x), gc.y - rhi(gc.y));
    GqL2.w[1] = pk2(gc.z - rhi(gc.z), gc.w - rhi(gc.w));
    GqL2.w[2] = pk2(gd.x - rhi(gd.x), gd.y - rhi(gd.y));
    GqL2.w[3] = pk2(gd.z - rhi(gd.z), gd.w - rhi(gd.w));
    __syncthreads();   // scheb + sLacc ready

    f32x16 Facc;
#pragma unroll
    for (int r = 0; r < 16; ++r) Facc[r] = 0.f;
    const float m2v = 2.0f / (float)(CHEB_B - CHEB_A);
    const float shv = (float)((CHEB_A + CHEB_B) / (CHEB_B - CHEB_A));
    const float tm = 2.f * m2v, tsh = -2.f * shv;
    const float cDv = scheb[DDEG], c0h = 0.5f * scheb[0];

    // constant cD*I Clenshaw-seed B-fragments (matrix-independent -> hoisted)
    FB CDB1, CDB2;
    {
        f32x16 cDdm;
#pragma unroll
        for (int r = 0; r < 16; ++r) cDdm[r] = cDv * dm[r];
        toB<false>(cDdm, CDB1, CDB2);
    }

    for (int m = blockIdx.x * 4 + wv; m < NMAT; m += NWAVES) {
        const float* Xm = Xg + (size_t)m * 1024 + col * 32 + 8 * h;
        float4 xa = *(const float4*)(Xm);
        float4 xb = *(const float4*)(Xm + 4);
        float4 xc = *(const float4*)(Xm + 16);
        float4 xd = *(const float4*)(Xm + 20);
        FB AX1, AX2;
        AX1.w[0] = cvt2(xa.x, xa.y); AX1.w[1] = cvt2(xa.z, xa.w);
        AX1.w[2] = cvt2(xb.x, xb.y); AX1.w[3] = cvt2(xb.z, xb.w);
        AX2.w[0] = cvt2(xc.x, xc.y); AX2.w[1] = cvt2(xc.z, xc.w);
        AX2.w[2] = cvt2(xd.x, xd.y); AX2.w[3] = cvt2(xd.z, xd.w);

        // U = X * Gq   (X symmetric -> direct A-frags; Gq split hi+lo)
        f32x16 U;
#pragma unroll
        for (int r = 0; r < 16; ++r) U[r] = 0.f;
        U = MFMA(AX2.v, GqL2.v, U); U = MFMA(AX1.v, GqL1.v, U);
        U = MFMA(AX2.v, GqH2.v, U); U = MFMA(AX1.v, GqH1.v, U);
        FB B1, B2;
        toB<false>(U, B1, B2);
        // S = Gq * U
        f32x16 S;
#pragma unroll
        for (int r = 0; r < 16; ++r) S[r] = 0.f;
        S = MFMA(GqL2.v, B2.v, S); S = MFMA(GqL1.v, B1.v, S);
        S = MFMA(GqH2.v, B2.v, S); S = MFMA(GqH1.v, B1.v, S);
        // 2*Shat = tm*S + tsh*I  -> A-operand frags (symmetric)
        f32x16 T;
#pragma unroll
        for (int r = 0; r < 16; ++r) T[r] = fmaf(tm, S[r], tsh * dm[r]);
        FB A1, A2;
        toB<false>(T, A1, A2);

        // Clenshaw: b_k = c_k I - b_{k+2} + (2Shat)*b_{k+1}
        f32x16 X0, X1;
#pragma unroll
        for (int r = 0; r < 16; ++r) { X1[r] = cDv * dm[r]; X0[r] = 0.f; }
        B1 = CDB1; B2 = CDB2;
        for (int it = 0; it < NITER; ++it) {
            float ka = scheb[DDEG - 1 - 2 * it];
            float kb = scheb[DDEG - 2 - 2 * it];
#pragma unroll
            for (int r = 0; r < 16; ++r) X0[r] = fmaf(ka, dm[r], -X0[r]);
            X0 = MFMA(A2.v, B2.v, X0); X0 = MFMA(A1.v, B1.v, X0);
            toB<false>(X0, B1, B2);
#pragma unroll
            for (int r = 0; r < 16; ++r) X1[r] = fmaf(kb, dm[r], -X1[r]);
            X1 = MFMA(A2.v, B2.v, X1); X1 = MFMA(A1.v, B1.v, X1);
            if (it < NITER - 1) toB<false>(X1, B1, B2);
            else                toB<true>(X1, B1, B2);   // 0.5*b_1
        }
        // f = 0.5*c0 I - b_2 + (2Shat)*(0.5 b_1)
#pragma unroll
        for (int r = 0; r < 16; ++r) X0[r] = fmaf(c0h, dm[r], -X0[r]);
        X0 = MFMA(A2.v, B2.v, X0); X0 = MFMA(A1.v, B1.v, X0);
#pragma unroll
        for (int r = 0; r < 16; ++r) Facc[r] += X0[r];
    }
#pragma unroll
    for (int r = 0; r < 16; ++r) {
        int row = (r & 3) + 8 * (r >> 2) + 4 * h;
        atomicAdd(&sLacc[row * 32 + col], Facc[r]);
    }
    __syncthreads();
    float4 v = *(float4*)&sLacc[4 * t];
    ((float4*)pL)[(size_t)blockIdx.x * 256 + t] = v;
}

// ---------------- K3b: reduce 2048 partials -> 32 ----------------
__global__ __launch_bounds__(256) void k_red32(const float4* __restrict__ pL4,
                                               float4* __restrict__ pL24) {
    int b = blockIdx.x, t = threadIdx.x;
    float4 acc = { 0.f, 0.f, 0.f, 0.f };
    for (int r = 0; r < 64; ++r) {
        float4 v = pL4[(size_t)(b * 64 + r) * 256 + t];
        acc.x += v.x; acc.y += v.y; acc.z += v.z; acc.w += v.w;
    }
    pL24[b * 256 + t] = acc;
}

// ---------------- K4: L -> expL -> Gn -> Gn^{-1/2}; W^{1/2}; C = Wsq*Gn_isq ----------------
__global__ __launch_bounds__(256) void k_final(const float4* __restrict__ pL24,
                                               const float* __restrict__ Wg,
                                               float* __restrict__ ws) {
    __shared__ alignas(16) float B0[1024], B1[1024], B2[1024], B3[1024], B4[1024], B5[1024], B6[1024];
    __shared__ float sc[4];
    int t = threadIdx.x;
    int i = t >> 3, j0 = (t & 7) * 4;
    if (t == 0) { sc[2] = 0.f; }
    float4 acc = { 0.f, 0.f, 0.f, 0.f };
    for (int b = 0; b < 32; ++b) {
        float4 v = pL24[b * 256 + t];
        acc.x += v.x; acc.y += v.y; acc.z += v.z; acc.w += v.w;
    }
    const float invM = 1.0f / (float)NMAT;
    B0[4 * t + 0] = acc.x * invM; B0[4 * t + 1] = acc.y * invM;
    B0[4 * t + 2] = acc.z * invM; B0[4 * t + 3] = acc.w * invM;
    __syncthreads();
    if (t == 0) { float s = 0.f; for (int d = 0; d < 32; ++d) s += B0[d * 33]; sc[0] = s / 32.0f; }
    __syncthreads();
    float s0 = sc[0];
#pragma unroll
    for (int q = 0; q < 4; ++q) {
        int e = i * 32 + j0 + q;
        B1[e] = B0[e] - ((i == j0 + q) ? s0 : 0.f);   // L0
    }
    __syncthreads();
#pragma unroll
    for (int q = 0; q < 4; ++q) {
        int e = i * 32 + j0 + q;
        float d = (i == j0 + q) ? 1.f : 0.f;
        B2[e] = B1[e];
        B4[e] = d + B1[e];
    }
    __syncthreads();
    {
        float* P = B2; float* Pn = B3;
        for (int k = 2; k <= 12; ++k) {
            mm32(P, B1, Pn, t);
            __syncthreads();
            float invk = 1.0f / (float)k;
#pragma unroll
            for (int q = 0; q < 4; ++q) {
                int e = i * 32 + j0 + q;
                Pn[e] *= invk;
                B4[e] += Pn[e];
            }
            float* tmp = P; P = Pn; Pn = tmp;
            __syncthreads();
        }
    }
    float es = expf(s0);
#pragma unroll
    for (int q = 0; q < 4; ++q) B4[i * 32 + j0 + q] *= es;   // expL
    __syncthreads();
    for (int e = t; e < 1024; e += 256) B5[e] = ws[WS_GSQ + e];
    __syncthreads();
    mm32(B5, B4, B6, t); __syncthreads();
    mm32(B6, B5, B0, t); __syncthreads();                    // Gn in B0
    if (t == 0) { float s = 0.f; for (int d = 0; d < 32; ++d) s += B0[d * 33]; sc[1] = s / 32.0f; }
    __syncthreads();
    float c2 = sc[1];
#pragma unroll
    for (int q = 0; q < 4; ++q) {
        int e = i * 32 + j0 + q;
        B2[e] = B0[e] / c2;
        B3[e] = (i == j0 + q) ? 1.f : 0.f;
    }
    __syncthreads();
    {   // coupled NS for Gn/c2: Z->rsqrt
        float* Y = B2; float* Z = B3; float* T = B6; float* Ya = B1; float* Zb = B4;
        for (int it = 0; it < 8; ++it) {
            mm32(Z, Y, T, t); __syncthreads();
#pragma unroll
            for (int q = 0; q < 4; ++q) {
                int e = i * 32 + j0 + q;
                T[e] = 0.5f * (3.f * ((i == j0 + q) ? 1.f : 0.f) - T[e]);
            }
            __syncthreads();
            mm32(Y, T, Ya, t); mm32(T, Z, Zb, t); __syncthreads();
            float* tmp = Y; Y = Ya; Ya = tmp;
            tmp = Z; Z = Zb; Zb = tmp;
        }
        float rc2 = rsqrtf(c2);
#pragma unroll
        for (int q = 0; q < 4; ++q) {
            int e = i * 32 + j0 + q;
            B5[e] = Z[e] * rc2;      // Gn^{-1/2}
        }
    }
    __syncthreads();
    for (int e = t; e < 1024; e += 256) B0[e] = Wg[e];
    __syncthreads();
    {
        float ls = 0.f;
#pragma unroll
        for (int q = 0; q < 4; ++q) { float w = B0[i * 32 + j0 + q]; ls += w * w; }
        atomicAdd(&sc[2], ls);
    }
    __syncthreads();
    float c3 = sqrtf(sc[2]);
#pragma unroll
    for (int q = 0; q < 4; ++q) {
        int e = i * 32 + j0 + q;
        B2[e] = B0[e] / c3;
        B3[e] = (i == j0 + q) ? 1.f : 0.f;
    }
    __syncthreads();
    {
        float* Y = B2; float* Z = B3; float* T = B6; float* Ya = B1; float* Zb = B4;
        for (int it = 0; it < 15; ++it) {
            mm32(Z, Y, T, t); __syncthreads();
#pragma unroll
            for (int q = 0; q < 4; ++q) {
                int e = i * 32 + j0 + q;
                T[e] = 0.5f * (3.f * ((i == j0 + q) ? 1.f : 0.f) - T[e]);
            }
            __syncthreads();
            mm32(Y, T, Ya, t); mm32(T, Z, Zb, t); __syncthreads();
            float* tmp = Y; Y = Ya; Ya = tmp;
            tmp = Z; Z = Zb; Zb = tmp;
        }
        float rc3 = sqrtf(c3);
#pragma unroll
        for (int q = 0; q < 4; ++q) {
            int e = i * 32 + j0 + q;
            B0[e] = Y[e] * rc3;      // W^{1/2}
        }
    }
    __syncthreads();
    mm32(B0, B5, B6, t); __syncthreads();   // C = Wsq * Gn_isq
#pragma unroll
    for (int q = 0; q < 4; ++q) {
        int e = i * 32 + j0 + q;
        ws[WS_C + e] = B6[e];
        ws[WS_CT + (j0 + q) * 32 + i] = B6[e];
    }
}

// ---------------- K5: out = C * X * C^T ----------------
__global__ __launch_bounds__(256) void k_out(const float* __restrict__ Xg,
                                             const float* __restrict__ ws,
                                             float* __restrict__ Og) {
    __shared__ alignas(16) float sCT[1024];
    __shared__ alignas(16) float sX[1024];
    __shared__ alignas(16) float sTt[33 * 32];
    int t = threadIdx.x;
    int i = t >> 3, j0 = (t & 7) * 4;
    for (int e = t; e < 1024; e += 256) sCT[e] = ws[WS_CT + e];
    __syncthreads();
    for (int r = 0; r < 8; ++r) {
        int m = blockIdx.x * 8 + r;
        const float4* Xm4 = (const float4*)(Xg + (size_t)m * 1024);
        *(float4*)&sX[4 * t] = Xm4[t];
        __syncthreads();
        float ax = 0.f, ay = 0.f, az = 0.f, aw = 0.f;
#pragma unroll
        for (int k = 0; k < 32; ++k) {
            float cv = sCT[k * 32 + i];
            float4 xv = *(const float4*)&sX[k * 32 + j0];
            ax += cv * xv.x; ay += cv * xv.y; az += cv * xv.z; aw += cv * xv.w;
        }
        sTt[(j0 + 0) * 33 + i] = ax; sTt[(j0 + 1) * 33 + i] = ay;
        sTt[(j0 + 2) * 33 + i] = az; sTt[(j0 + 3) * 33 + i] = aw;
        __syncthreads();
        ax = ay = az = aw = 0.f;
#pragma unroll
        for (int k = 0; k < 32; ++k) {
            float tv = sTt[k * 33 + i];
            float4 cv = *(const float4*)&sCT[k * 32 + j0];
            ax += tv * cv.x; ay += tv * cv.y; az += tv * cv.z; aw += tv * cv.w;
        }
        float4 r4 = { ax, ay, az, aw };
        *(float4*)&Og[(size_t)m * 1024 + i * 32 + j0] = r4;
        __syncthreads();
    }
}

extern "C" void kernel_launch(void* const* d_in, const int* in_sizes, int n_in,
                              void* d_out, int out_size, void* d_ws, size_t ws_size,
                              hipStream_t stream) {
    const float* X = (const float*)d_in[0];
    const float* W = (const float*)d_in[1];
    float* out = (float*)d_out;
    float* ws  = (float*)d_ws;
    float* pA  = out + OUT_PA;
    float* pL  = out + OUT_PL;
    float* pL2 = out + OUT_PL2;

    hipLaunchKernelGGL(k_psum,   dim3(256),     dim3(256), 0, stream, (const float4*)X, (float4*)pA);
    hipLaunchKernelGGL(k_setup,  dim3(1),       dim3(256), 0, stream, (const float4*)pA, ws);
    hipLaunchKernelGGL(k_logsum, dim3(NLOGBLK), dim3(256), 0, stream, X, ws, pL);
    hipLaunchKernelGGL(k_red32,  dim3(32),      dim3(256), 0, stream, (const float4*)pL, (float4*)pL2);
    hipLaunchKernelGGL(k_final,  dim3(1),       dim3(256), 0, stream, (const float4*)pL2, W, ws);
    hipLaunchKernelGGL(k_out,    dim3(2048),    dim3(256), 0, stream, X, ws, out);
}

// Round 6
// 283.821 us; speedup vs baseline: 1.2674x; 1.1941x over previous
//
#include <hip/hip_runtime.h>
#include <math.h>

#define NMAT   16384
#define CHEB_A 0.08
#define CHEB_B 7.0
#define DDEG   29            // Chebyshev degree (odd); truncation tail ~5e-4 on [a,b]
#define NCOEF  (DDEG + 1)
#define NITER  ((DDEG - 1) / 2)   // Clenshaw pair-iterations
#define NLOGBLK 2048         // k_logsum blocks
#define NWAVES (NLOGBLK * 4) // 8192 waves -> exactly 2 matrices per wave

// ws float layout
#define WS_GQ    0
#define WS_GSQ   1024
#define WS_C     2112
#define WS_CT    3136

// d_out float scratch layout (consumed before final kernel overwrites):
#define OUT_PA   0          // 256*1024  (stage-1 partial sums of X)
#define OUT_PL   262144     // 2048*1024 (stage-3 partial sums of log)
#define OUT_PL2  2359296    // 32*1024

typedef __attribute__((ext_vector_type(8)))  short short8;   // 8 bf16 (4 VGPRs)
typedef __attribute__((ext_vector_type(16))) float f32x16;   // MFMA 32x32 C/D
typedef __attribute__((ext_vector_type(2)))  float f32x2;
typedef __attribute__((ext_vector_type(2)))  __bf16 bf16x2;

union FB { short8 v; unsigned int w[4]; };

// row of C/D-layout register r for half h: (r&3) + 8*(r>>2) + 4*h
#define ROWOF(r, h) (((r) & 3) + 8 * ((r) >> 2) + 4 * (h))

// round-half-up f32->bf16, pack pair into one dword (lo=a, hi=b). Split-path
// (keeps hi/lo splits exactly consistent with rhi()).
__device__ __forceinline__ unsigned int pk2(float a, float b) {
    unsigned int au = __float_as_uint(a) + 0x8000u;
    unsigned int bu = __float_as_uint(b) + 0x8000u;
    return __builtin_amdgcn_perm(bu, au, 0x07060302u);
}
__device__ __forceinline__ float rhi(float x) {   // bf16-rounded value as float
    return __uint_as_float((__float_as_uint(x) + 0x8000u) & 0xffff0000u);
}

// hot-path pack: RNE pack of 2 f32 -> 2 bf16 (lo=a, hi=b), compiler-emitted
// (vector fptrunc; gfx950 backend selects v_cvt_pk_bf16_f32 itself).
__device__ __forceinline__ unsigned int cvt2(float a, float b) {
    f32x2 s; s.x = a; s.y = b;
    bf16x2 t = __builtin_convertvector(s, bf16x2);
    unsigned int r;
    __builtin_memcpy(&r, &t, 4);
    return r;
}

// D (C/D layout fp32) -> two B-operand k-half fragments, pure in-register.
// C/D layout is column-owned (lane holds col=lane&31, rows (r&3)+8*(r>>2)+4h);
// B layout is also column-owned (lane holds col, k=8h+e). The only data motion
// needed is a half-wave exchange lane <-> lane^32: v_permlane32_swap_b32.
template <bool HALF>
__device__ __forceinline__ void toB(const f32x16& d, FB& b1, FB& b2) {
    unsigned int p[8];
#pragma unroll
    for (int g = 0; g < 8; ++g) {
        float s0 = HALF ? 0.5f * d[2 * g]     : d[2 * g];
        float s1 = HALF ? 0.5f * d[2 * g + 1] : d[2 * g + 1];
        p[g] = cvt2(s0, s1);
    }
    auto r02 = __builtin_amdgcn_permlane32_swap(p[0], p[2], false, false);
    auto r13 = __builtin_amdgcn_permlane32_swap(p[1], p[3], false, false);
    auto r46 = __builtin_amdgcn_permlane32_swap(p[4], p[6], false, false);
    auto r57 = __builtin_amdgcn_permlane32_swap(p[5], p[7], false, false);
    b1.w[0] = r02[0]; b1.w[1] = r13[0]; b1.w[2] = r02[1]; b1.w[3] = r13[1];
    b2.w[0] = r46[0]; b2.w[1] = r57[0]; b2.w[2] = r46[1]; b2.w[3] = r57[1];
}

#define MFMA(a, b, c) __builtin_amdgcn_mfma_f32_32x32x16_bf16((a), (b), (c), 0, 0, 0)

// ---- hi/lo split fragments of a symmetric matrix in C/D layout.
// For symmetric M, these serve as BOTH A- and B-operand fragments (k_logsum's
// proven Gq property). hi uses pk2 (half-up); lo = pk2(x - rhi(x)) — the exact
// residual recipe from the Gq path.
struct SplitM { FB h1, h2, l1, l2; };

__device__ __forceinline__ void splitB(const f32x16& d, SplitM& s) {
    unsigned int ph[8], pl[8];
#pragma unroll
    for (int g = 0; g < 8; ++g) {
        float a = d[2 * g], b = d[2 * g + 1];
        ph[g] = pk2(a, b);
        pl[g] = pk2(a - rhi(a), b - rhi(b));
    }
    auto h02 = __builtin_amdgcn_permlane32_swap(ph[0], ph[2], false, false);
    auto h13 = __builtin_amdgcn_permlane32_swap(ph[1], ph[3], false, false);
    auto h46 = __builtin_amdgcn_permlane32_swap(ph[4], ph[6], false, false);
    auto h57 = __builtin_amdgcn_permlane32_swap(ph[5], ph[7], false, false);
    s.h1.w[0] = h02[0]; s.h1.w[1] = h13[0]; s.h1.w[2] = h02[1]; s.h1.w[3] = h13[1];
    s.h2.w[0] = h46[0]; s.h2.w[1] = h57[0]; s.h2.w[2] = h46[1]; s.h2.w[3] = h57[1];
    auto l02 = __builtin_amdgcn_permlane32_swap(pl[0], pl[2], false, false);
    auto l13 = __builtin_amdgcn_permlane32_swap(pl[1], pl[3], false, false);
    auto l46 = __builtin_amdgcn_permlane32_swap(pl[4], pl[6], false, false);
    auto l57 = __builtin_amdgcn_permlane32_swap(pl[5], pl[7], false, false);
    s.l1.w[0] = l02[0]; s.l1.w[1] = l13[0]; s.l1.w[2] = l02[1]; s.l1.w[3] = l13[1];
    s.l2.w[0] = l46[0]; s.l2.w[1] = l57[0]; s.l2.w[2] = l46[1]; s.l2.w[3] = l57[1];
}

// D = A*B for split operands; A must be symmetric (A-frags == its toB frags).
// 3 product terms (hi*hi + hi*lo + lo*hi), 2 k-halves each = 6 MFMAs. ~2^-16 rel.
__device__ __forceinline__ f32x16 mulSS(const SplitM& A, const SplitM& B) {
    f32x16 d;
#pragma unroll
    for (int r = 0; r < 16; ++r) d[r] = 0.f;
    d = MFMA(A.h2.v, B.l2.v, d); d = MFMA(A.h1.v, B.l1.v, d);
    d = MFMA(A.l2.v, B.h2.v, d); d = MFMA(A.l1.v, B.h1.v, d);
    d = MFMA(A.h2.v, B.h2.v, d); d = MFMA(A.h1.v, B.h1.v, d);
    return d;
}

__device__ __forceinline__ float wred(float v) {   // 64-lane sum, broadcast
    v += __shfl_xor(v, 32);
    v += __shfl_xor(v, 16);
    v += __shfl_xor(v, 8);
    v += __shfl_xor(v, 4);
    v += __shfl_xor(v, 2);
    v += __shfl_xor(v, 1);
    return v;
}

// ---------------- block-level 32x32 matmul on LDS (row-major), 256 threads ----------------
__device__ __forceinline__ void mm32(const float* A, const float* B, float* D, int t) {
    int i = t >> 3, j0 = (t & 7) * 4;
    float a[32];
#pragma unroll
    for (int q = 0; q < 8; ++q) {
        float4 v = *(const float4*)&A[i * 32 + q * 4];
        a[4 * q] = v.x; a[4 * q + 1] = v.y; a[4 * q + 2] = v.z; a[4 * q + 3] = v.w;
    }
    float ax = 0.f, ay = 0.f, az = 0.f, aw = 0.f;
#pragma unroll
    for (int k = 0; k < 32; ++k) {
        float4 bv = *(const float4*)&B[k * 32 + j0];
        ax += a[k] * bv.x; ay += a[k] * bv.y; az += a[k] * bv.z; aw += a[k] * bv.w;
    }
    float4 r = { ax, ay, az, aw };
    *(float4*)&D[i * 32 + j0] = r;
}

// ---------------- K1: partial sums (256 blocks x 64 matrices) ----------------
__global__ __launch_bounds__(256) void k_psum(const float4* __restrict__ X4,
                                              float4* __restrict__ pA4) {
    int b = blockIdx.x, t = threadIdx.x;
    float4 acc = { 0.f, 0.f, 0.f, 0.f };
    for (int r = 0; r < 64; ++r) {
        float4 v = X4[(size_t)(b * 64 + r) * 256 + t];
        acc.x += v.x; acc.y += v.y; acc.z += v.z; acc.w += v.w;
    }
    pA4[b * 256 + t] = acc;
}

// ---------------- K2: finalize G, G^{1/2}, G^{-1/2} ----------------
__global__ __launch_bounds__(256) void k_setup(const float4* __restrict__ pA4,
                                               float* __restrict__ ws) {
    __shared__ alignas(16) float sG[1024], sE[1024], sPa[1024], sPb[1024], sS1[1024], sS2[1024];
    __shared__ float sc[2];
    int t = threadIdx.x;
    float4 acc = { 0.f, 0.f, 0.f, 0.f };
    for (int b = 0; b < 256; ++b) {
        float4 v = pA4[b * 256 + t];
        acc.x += v.x; acc.y += v.y; acc.z += v.z; acc.w += v.w;
    }
    const float invM = 1.0f / (float)NMAT;
    sG[4 * t + 0] = acc.x * invM; sG[4 * t + 1] = acc.y * invM;
    sG[4 * t + 2] = acc.z * invM; sG[4 * t + 3] = acc.w * invM;
    __syncthreads();
    if (t == 0) { float s = 0.f; for (int d = 0; d < 32; ++d) s += sG[d * 33]; sc[0] = s / 32.0f; }
    __syncthreads();
    float c = sc[0];
    int i = t >> 3, j0 = (t & 7) * 4;
#pragma unroll
    for (int q = 0; q < 4; ++q) {
        int e = i * 32 + j0 + q;
        sE[e] = sG[e] / c - ((i == j0 + q) ? 1.f : 0.f);
    }
    __syncthreads();
    const float alp[9] = { 1.f, 0.5f, -0.125f, 0.0625f, -0.0390625f, 0.02734375f,
                           -0.0205078125f, 0.01611328125f, -0.013092041015625f };
    const float bet[9] = { 1.f, -0.5f, 0.375f, -0.3125f, 0.2734375f, -0.24609375f,
                           0.2255859375f, -0.20947265625f, 0.196380615234375f };
#pragma unroll
    for (int q = 0; q < 4; ++q) {
        int e = i * 32 + j0 + q;
        float d = (i == j0 + q) ? 1.f : 0.f;
        sS1[e] = d + alp[1] * sE[e];
        sS2[e] = d + bet[1] * sE[e];
        sPa[e] = sE[e];
    }
    __syncthreads();
    {
        float* P = sPa; float* Pn = sPb;
        for (int k = 2; k <= 8; ++k) {
            mm32(P, sE, Pn, t);
            __syncthreads();
#pragma unroll
            for (int q = 0; q < 4; ++q) {
                int e = i * 32 + j0 + q;
                sS1[e] += alp[k] * Pn[e];
                sS2[e] += bet[k] * Pn[e];
            }
            float* tmp = P; P = Pn; Pn = tmp;
            __syncthreads();
        }
    }
    float rc = sqrtf(c);
#pragma unroll
    for (int q = 0; q < 4; ++q) {
        int e = i * 32 + j0 + q;
        ws[WS_GSQ + e] = rc * sS1[e];
        ws[WS_GQ + e]  = sS2[e] / rc;
    }
}

// ---------------- K3: sum of matrix logs, MFMA Clenshaw ----------------
__global__ __launch_bounds__(256, 4) void k_logsum(const float* __restrict__ Xg,
                                                   const float* __restrict__ ws,
                                                   float* __restrict__ pL) {
    __shared__ float sLacc[1024];
    __shared__ float scheb[NCOEF];
    int t = threadIdx.x;
    for (int e = t; e < 1024; e += 256) sLacc[e] = 0.f;
    if (t < NCOEF) {
        // closed-form Chebyshev coeffs of log on [a,b]
        float alpha = 0.5f * (float)(CHEB_A + CHEB_B);
        float beta  = 0.5f * (float)(CHEB_B - CHEB_A);
        float dd = beta / alpha, s = sqrtf(1.f - dd * dd), tt = dd / (1.f + s);
        float v;
        if (t == 0) v = 2.f * (logf(alpha) + logf(0.5f * (1.f + s)));
        else        v = 2.f * ((t & 1) ? 1.f : -1.f) * exp2f((float)t * log2f(tt)) / (float)t;
        scheb[t] = v;
    }
    const int wv = t >> 6, lane = t & 63, h = lane >> 5, col = lane & 31;

    // diagonal mask in C/D layout: row(reg)=(reg&3)+8*(reg>>2)+4h == col
    int hasd = (((col >> 2) & 1) == h);
    int dreg = 4 * (col >> 3) + (col & 3);
    f32x16 dm;
#pragma unroll
    for (int r = 0; r < 16; ++r) dm[r] = (hasd && r == dreg) ? 1.f : 0.f;

    // Gq fragments (symmetric; same regs serve as A- and B-operand), hi/lo split
    const float* Gqp = ws + WS_GQ + col * 32 + 8 * h;
    float4 ga = *(const float4*)(Gqp);
    float4 gb = *(const float4*)(Gqp + 4);
    float4 gc = *(const float4*)(Gqp + 16);
    float4 gd = *(const float4*)(Gqp + 20);
    FB GqH1, GqH2, GqL1, GqL2;
    GqH1.w[0] = pk2(ga.x, ga.y); GqH1.w[1] = pk2(ga.z, ga.w);
    GqH1.w[2] = pk2(gb.x, gb.y); GqH1.w[3] = pk2(gb.z, gb.w);
    GqH2.w[0] = pk2(gc.x, gc.y); GqH2.w[1] = pk2(gc.z, gc.w);
    GqH2.w[2] = pk2(gd.x, gd.y); GqH2.w[3] = pk2(gd.z, gd.w);
    GqL1.w[0] = pk2(ga.x - rhi(ga.x), ga.y - rhi(ga.y));
    GqL1.w[1] = pk2(ga.z - rhi(ga.z), ga.w - rhi(ga.w));
    GqL1.w[2] = pk2(gb.x - rhi(gb.x), gb.y - rhi(gb.y));
    GqL1.w[3] = pk2(gb.z - rhi(gb.z), gb.w - rhi(gb.w));
    GqL2.w[0] = pk2(gc.x - rhi(gc.x), gc.y - rhi(gc.y));
    GqL2.w[1] = pk2(gc.z - rhi(gc.z), gc.w - rhi(gc.w));
    GqL2.w[2] = pk2(gd.x - rhi(gd.x), gd.y - rhi(gd.y));
    GqL2.w[3] = pk2(gd.z - rhi(gd.z), gd.w - rhi(gd.w));
    __syncthreads();   // scheb + sLacc ready

    f32x16 Facc;
#pragma unroll
    for (int r = 0; r < 16; ++r) Facc[r] = 0.f;
    const float m2v = 2.0f / (float)(CHEB_B - CHEB_A);
    const float shv = (float)((CHEB_A + CHEB_B) / (CHEB_B - CHEB_A));
    const float tm = 2.f * m2v, tsh = -2.f * shv;
    const float cDv = scheb[DDEG], c0h = 0.5f * scheb[0];

    // constant cD*I Clenshaw-seed B-fragments (matrix-independent -> hoisted)
    FB CDB1, CDB2;
    {
        f32x16 cDdm;
#pragma unroll
        for (int r = 0; r < 16; ++r) cDdm[r] = cDv * dm[r];
        toB<false>(cDdm, CDB1, CDB2);
    }

    for (int m = blockIdx.x * 4 + wv; m < NMAT; m += NWAVES) {
        const float* Xm = Xg + (size_t)m * 1024 + col * 32 + 8 * h;
        float4 xa = *(const float4*)(Xm);
        float4 xb = *(const float4*)(Xm + 4);
        float4 xc = *(const float4*)(Xm + 16);
        float4 xd = *(const float4*)(Xm + 20);
        FB AX1, AX2;
        AX1.w[0] = cvt2(xa.x, xa.y); AX1.w[1] = cvt2(xa.z, xa.w);
        AX1.w[2] = cvt2(xb.x, xb.y); AX1.w[3] = cvt2(xb.z, xb.w);
        AX2.w[0] = cvt2(xc.x, xc.y); AX2.w[1] = cvt2(xc.z, xc.w);
        AX2.w[2] = cvt2(xd.x, xd.y); AX2.w[3] = cvt2(xd.z, xd.w);

        // U = X * Gq   (X symmetric -> direct A-frags; Gq split hi+lo)
        f32x16 U;
#pragma unroll
        for (int r = 0; r < 16; ++r) U[r] = 0.f;
        U = MFMA(AX2.v, GqL2.v, U); U = MFMA(AX1.v, GqL1.v, U);
        U = MFMA(AX2.v, GqH2.v, U); U = MFMA(AX1.v, GqH1.v, U);
        FB B1, B2;
        toB<false>(U, B1, B2);
        // S = Gq * U
        f32x16 S;
#pragma unroll
        for (int r = 0; r < 16; ++r) S[r] = 0.f;
        S = MFMA(GqL2.v, B2.v, S); S = MFMA(GqL1.v, B1.v, S);
        S = MFMA(GqH2.v, B2.v, S); S = MFMA(GqH1.v, B1.v, S);
        // 2*Shat = tm*S + tsh*I  -> A-operand frags (symmetric)
        f32x16 T;
#pragma unroll
        for (int r = 0; r < 16; ++r) T[r] = fmaf(tm, S[r], tsh * dm[r]);
        FB A1, A2;
        toB<false>(T, A1, A2);

        // Clenshaw: b_k = c_k I - b_{k+2} + (2Shat)*b_{k+1}
        f32x16 X0, X1;
#pragma unroll
        for (int r = 0; r < 16; ++r) { X1[r] = cDv * dm[r]; X0[r] = 0.f; }
        B1 = CDB1; B2 = CDB2;
        for (int it = 0; it < NITER; ++it) {
            float ka = scheb[DDEG - 1 - 2 * it];
            float kb = scheb[DDEG - 2 - 2 * it];
#pragma unroll
            for (int r = 0; r < 16; ++r) X0[r] = fmaf(ka, dm[r], -X0[r]);
            X0 = MFMA(A2.v, B2.v, X0); X0 = MFMA(A1.v, B1.v, X0);
            toB<false>(X0, B1, B2);
#pragma unroll
            for (int r = 0; r < 16; ++r) X1[r] = fmaf(kb, dm[r], -X1[r]);
            X1 = MFMA(A2.v, B2.v, X1); X1 = MFMA(A1.v, B1.v, X1);
            if (it < NITER - 1) toB<false>(X1, B1, B2);
            else                toB<true>(X1, B1, B2);   // 0.5*b_1
        }
        // f = 0.5*c0 I - b_2 + (2Shat)*(0.5 b_1)
#pragma unroll
        for (int r = 0; r < 16; ++r) X0[r] = fmaf(c0h, dm[r], -X0[r]);
        X0 = MFMA(A2.v, B2.v, X0); X0 = MFMA(A1.v, B1.v, X0);
#pragma unroll
        for (int r = 0; r < 16; ++r) Facc[r] += X0[r];
    }
#pragma unroll
    for (int r = 0; r < 16; ++r) {
        int row = (r & 3) + 8 * (r >> 2) + 4 * h;
        atomicAdd(&sLacc[row * 32 + col], Facc[r]);
    }
    __syncthreads();
    float4 v = *(float4*)&sLacc[4 * t];
    ((float4*)pL)[(size_t)blockIdx.x * 256 + t] = v;
}

// ---------------- K3b: reduce 2048 partials -> 32 ----------------
__global__ __launch_bounds__(256) void k_red32(const float4* __restrict__ pL4,
                                               float4* __restrict__ pL24) {
    int b = blockIdx.x, t = threadIdx.x;
    float4 acc = { 0.f, 0.f, 0.f, 0.f };
    for (int r = 0; r < 64; ++r) {
        float4 v = pL4[(size_t)(b * 64 + r) * 256 + t];
        acc.x += v.x; acc.y += v.y; acc.z += v.z; acc.w += v.w;
    }
    pL24[b * 256 + t] = acc;
}

// ---------------- K4: single-wave MFMA chain: L -> expL -> Gn -> Gn^{-1/2};
//                  W^{1/2}; C = Wsq*Gn_isq. All matrices in C/D-layout registers;
//                  every product via split-bf16 MFMA (A always symmetric). ----------------
__global__ __launch_bounds__(256) void k_final(const float4* __restrict__ pL24,
                                               const float* __restrict__ Wg,
                                               float* __restrict__ ws) {
    __shared__ alignas(16) float sL[1024];
    int t = threadIdx.x;
    // stage: all 256 threads reduce the 32 partials
    {
        float4 acc = { 0.f, 0.f, 0.f, 0.f };
        for (int b = 0; b < 32; ++b) {
            float4 v = pL24[b * 256 + t];
            acc.x += v.x; acc.y += v.y; acc.z += v.z; acc.w += v.w;
        }
        const float invM = 1.0f / (float)NMAT;
        sL[4 * t + 0] = acc.x * invM; sL[4 * t + 1] = acc.y * invM;
        sL[4 * t + 2] = acc.z * invM; sL[4 * t + 3] = acc.w * invM;
    }
    __syncthreads();
    if (t >= 64) return;          // wave 0 only from here (no more barriers)

    const int h = t >> 5, col = t & 31;
    const int hasd = (((col >> 2) & 1) == h);
    const int dreg = 4 * (col >> 3) + (col & 3);
    f32x16 dm;
#pragma unroll
    for (int r = 0; r < 16; ++r) dm[r] = (hasd && r == dreg) ? 1.f : 0.f;

    // mean-L into C/D registers
    f32x16 Lm;
#pragma unroll
    for (int r = 0; r < 16; ++r) Lm[r] = sL[ROWOF(r, h) * 32 + col];

    // s0 = tr(L)/32
    float tr = 0.f;
#pragma unroll
    for (int r = 0; r < 16; ++r) tr = fmaf(Lm[r], dm[r], tr);
    float s0 = wred(tr) / 32.0f;

    f32x16 L0;
#pragma unroll
    for (int r = 0; r < 16; ++r) L0[r] = fmaf(-s0, dm[r], Lm[r]);

    // expm series: E4 = sum_{k=0}^{12} L0^k/k!
    SplitM SL0; splitB(L0, SL0);
    f32x16 E4;
#pragma unroll
    for (int r = 0; r < 16; ++r) E4[r] = dm[r] + L0[r];
    SplitM SP = SL0;
    for (int k = 2; k <= 12; ++k) {
        f32x16 Pn = mulSS(SP, SL0);        // P * L0 (A=P symmetric)
        float invk = 1.0f / (float)k;
#pragma unroll
        for (int r = 0; r < 16; ++r) { Pn[r] *= invk; E4[r] += Pn[r]; }
        if (k < 12) splitB(Pn, SP);
    }
    float es = expf(s0);
#pragma unroll
    for (int r = 0; r < 16; ++r) E4[r] *= es;   // expL

    // Gn = Gsq * (expL * Gsq)
    f32x16 Gs;
#pragma unroll
    for (int r = 0; r < 16; ++r) Gs[r] = ws[WS_GSQ + ROWOF(r, h) * 32 + col];
    SplitM SG; splitB(Gs, SG);
    SplitM SE; splitB(E4, SE);
    f32x16 Mx = mulSS(SE, SG);              // expL*Gsq (A=expL sym; Mx NOT sym)
    SplitM SM; splitB(Mx, SM);
    f32x16 Gn = mulSS(SG, SM);              // A=Gsq sym, B=Mx

    // c2 = tr(Gn)/32; coupled NS x8 for (Gn/c2)^{-1/2}
    float tr2 = 0.f;
#pragma unroll
    for (int r = 0; r < 16; ++r) tr2 = fmaf(Gn[r], dm[r], tr2);
    float c2 = wred(tr2) / 32.0f;
    float ic2 = 1.0f / c2;

    f32x16 YC, ZC;
#pragma unroll
    for (int r = 0; r < 16; ++r) { YC[r] = Gn[r] * ic2; ZC[r] = dm[r]; }
    SplitM SY, SZ, ST;
    splitB(YC, SY); splitB(ZC, SZ);
    for (int it = 0; it < 8; ++it) {
        f32x16 ZY = mulSS(SZ, SY);          // Z*Y (Z sym)
        f32x16 T;
#pragma unroll
        for (int r = 0; r < 16; ++r) T[r] = fmaf(1.5f, dm[r], -0.5f * ZY[r]);
        splitB(T, ST);
        f32x16 Yn = mulSS(SY, ST);          // Y*T (Y sym)
        f32x16 Zn = mulSS(ST, SZ);          // T*Z (T sym)
        YC = Yn; ZC = Zn;
        splitB(YC, SY); splitB(ZC, SZ);
    }
    float rc2 = rsqrtf(c2);
    f32x16 Gi;
#pragma unroll
    for (int r = 0; r < 16; ++r) Gi[r] = ZC[r] * rc2;   // Gn^{-1/2}
    SplitM SGi; splitB(Gi, SGi);

    // W^{1/2}: c3 = ||W||_F; NS x15
    f32x16 Wm;
#pragma unroll
    for (int r = 0; r < 16; ++r) Wm[r] = Wg[ROWOF(r, h) * 32 + col];
    float ss = 0.f;
#pragma unroll
    for (int r = 0; r < 16; ++r) ss = fmaf(Wm[r], Wm[r], ss);
    float c3 = sqrtf(wred(ss));
    float ic3 = 1.0f / c3;
#pragma unroll
    for (int r = 0; r < 16; ++r) { YC[r] = Wm[r] * ic3; ZC[r] = dm[r]; }
    splitB(YC, SY); splitB(ZC, SZ);
    for (int it = 0; it < 15; ++it) {
        f32x16 ZY = mulSS(SZ, SY);
        f32x16 T;
#pragma unroll
        for (int r = 0; r < 16; ++r) T[r] = fmaf(1.5f, dm[r], -0.5f * ZY[r]);
        splitB(T, ST);
        f32x16 Yn = mulSS(SY, ST);
        f32x16 Zn = mulSS(ST, SZ);
        YC = Yn; ZC = Zn;
        splitB(YC, SY); splitB(ZC, SZ);
    }
    float rc3 = sqrtf(c3);
    f32x16 Ws;
#pragma unroll
    for (int r = 0; r < 16; ++r) Ws[r] = YC[r] * rc3;   // W^{1/2}
    SplitM SW; splitB(Ws, SW);

    f32x16 C = mulSS(SW, SGi);              // C = Wsq * Gn_isq (Wsq sym)
#pragma unroll
    for (int r = 0; r < 16; ++r) {
        int row = ROWOF(r, h);
        ws[WS_C + row * 32 + col] = C[r];
        ws[WS_CT + col * 32 + row] = C[r];
    }
}

// ---------------- K5: out = C * X * C^T ----------------
__global__ __launch_bounds__(256) void k_out(const float* __restrict__ Xg,
                                             const float* __restrict__ ws,
                                             float* __restrict__ Og) {
    __shared__ alignas(16) float sCT[1024];
    __shared__ alignas(16) float sX[1024];
    __shared__ alignas(16) float sTt[33 * 32];
    int t = threadIdx.x;
    int i = t >> 3, j0 = (t & 7) * 4;
    for (int e = t; e < 1024; e += 256) sCT[e] = ws[WS_CT + e];
    __syncthreads();
    for (int r = 0; r < 8; ++r) {
        int m = blockIdx.x * 8 + r;
        const float4* Xm4 = (const float4*)(Xg + (size_t)m * 1024);
        *(float4*)&sX[4 * t] = Xm4[t];
        __syncthreads();
        float ax = 0.f, ay = 0.f, az = 0.f, aw = 0.f;
#pragma unroll
        for (int k = 0; k < 32; ++k) {
            float cv = sCT[k * 32 + i];
            float4 xv = *(const float4*)&sX[k * 32 + j0];
            ax += cv * xv.x; ay += cv * xv.y; az += cv * xv.z; aw += cv * xv.w;
        }
        sTt[(j0 + 0) * 33 + i] = ax; sTt[(j0 + 1) * 33 + i] = ay;
        sTt[(j0 + 2) * 33 + i] = az; sTt[(j0 + 3) * 33 + i] = aw;
        __syncthreads();
        ax = ay = az = aw = 0.f;
#pragma unroll
        for (int k = 0; k < 32; ++k) {
            float tv = sTt[k * 33 + i];
            float4 cv = *(const float4*)&sCT[k * 32 + j0];
            ax += tv * cv.x; ay += tv * cv.y; az += tv * cv.z; aw += tv * cv.w;
        }
        float4 r4 = { ax, ay, az, aw };
        *(float4*)&Og[(size_t)m * 1024 + i * 32 + j0] = r4;
        __syncthreads();
    }
}

extern "C" void kernel_launch(void* const* d_in, const int* in_sizes, int n_in,
                              void* d_out, int out_size, void* d_ws, size_t ws_size,
                              hipStream_t stream) {
    const float* X = (const float*)d_in[0];
    const float* W = (const float*)d_in[1];
    float* out = (float*)d_out;
    float* ws  = (float*)d_ws;
    float* pA  = out + OUT_PA;
    float* pL  = out + OUT_PL;
    float* pL2 = out + OUT_PL2;

    hipLaunchKernelGGL(k_psum,   dim3(256),     dim3(256), 0, stream, (const float4*)X, (float4*)pA);
    hipLaunchKernelGGL(k_setup,  dim3(1),       dim3(256), 0, stream, (const float4*)pA, ws);
    hipLaunchKernelGGL(k_logsum, dim3(NLOGBLK), dim3(256), 0, stream, X, ws, pL);
    hipLaunchKernelGGL(k_red32,  dim3(32),      dim3(256), 0, stream, (const float4*)pL, (float4*)pL2);
    hipLaunchKernelGGL(k_final,  dim3(1),       dim3(256), 0, stream, (const float4*)pL2, W, ws);
    hipLaunchKernelGGL(k_out,    dim3(2048),    dim3(256), 0, stream, X, ws, out);
}

// Round 7
// 280.558 us; speedup vs baseline: 1.2822x; 1.0116x over previous
//
#include <hip/hip_runtime.h>
#include <math.h>

#define NMAT   16384
#define CHEB_A 0.08
#define CHEB_B 7.0
#define DDEG   29            // Chebyshev degree (odd); truncation tail ~5e-4 on [a,b]
#define NCOEF  (DDEG + 1)
#define NITER  ((DDEG - 1) / 2)   // Clenshaw pair-iterations
#define NLOGBLK 2048         // k_logsum blocks
#define NWAVES (NLOGBLK * 4) // 8192 waves; each wave owns matrices m0 and m0+NWAVES

// ws float layout
#define WS_GQ    0
#define WS_GSQ   1024
#define WS_C     2112
#define WS_CT    3136

// d_out float scratch layout (consumed before final kernel overwrites):
#define OUT_PA   0          // 256*1024  (stage-1 partial sums of X)
#define OUT_PL   262144     // 2048*1024 (stage-3 partial sums of log)
#define OUT_PL2  2359296    // 32*1024

typedef __attribute__((ext_vector_type(8)))  short short8;   // 8 bf16 (4 VGPRs)
typedef __attribute__((ext_vector_type(16))) float f32x16;   // MFMA 32x32 C/D
typedef __attribute__((ext_vector_type(2)))  float f32x2;
typedef __attribute__((ext_vector_type(2)))  __bf16 bf16x2;

union FB { short8 v; unsigned int w[4]; };

// row of C/D-layout register r for half h: (r&3) + 8*(r>>2) + 4*h
#define ROWOF(r, h) (((r) & 3) + 8 * ((r) >> 2) + 4 * (h))

// round-half-up f32->bf16, pack pair into one dword (lo=a, hi=b). Split-path
// (keeps hi/lo splits exactly consistent with rhi()).
__device__ __forceinline__ unsigned int pk2(float a, float b) {
    unsigned int au = __float_as_uint(a) + 0x8000u;
    unsigned int bu = __float_as_uint(b) + 0x8000u;
    return __builtin_amdgcn_perm(bu, au, 0x07060302u);
}
__device__ __forceinline__ float rhi(float x) {   // bf16-rounded value as float
    return __uint_as_float((__float_as_uint(x) + 0x8000u) & 0xffff0000u);
}

// hot-path pack: RNE pack of 2 f32 -> 2 bf16 (lo=a, hi=b), compiler-emitted
// (vector fptrunc; gfx950 backend selects v_cvt_pk_bf16_f32 itself).
__device__ __forceinline__ unsigned int cvt2(float a, float b) {
    f32x2 s; s.x = a; s.y = b;
    bf16x2 t = __builtin_convertvector(s, bf16x2);
    unsigned int r;
    __builtin_memcpy(&r, &t, 4);
    return r;
}

// D (C/D layout fp32) -> two B-operand k-half fragments, pure in-register.
// C/D layout is column-owned (lane holds col=lane&31, rows (r&3)+8*(r>>2)+4h);
// B layout is also column-owned (lane holds col, k=8h+e). The only data motion
// needed is a half-wave exchange lane <-> lane^32: v_permlane32_swap_b32.
template <bool HALF>
__device__ __forceinline__ void toB(const f32x16& d, FB& b1, FB& b2) {
    unsigned int p[8];
#pragma unroll
    for (int g = 0; g < 8; ++g) {
        float s0 = HALF ? 0.5f * d[2 * g]     : d[2 * g];
        float s1 = HALF ? 0.5f * d[2 * g + 1] : d[2 * g + 1];
        p[g] = cvt2(s0, s1);
    }
    auto r02 = __builtin_amdgcn_permlane32_swap(p[0], p[2], false, false);
    auto r13 = __builtin_amdgcn_permlane32_swap(p[1], p[3], false, false);
    auto r46 = __builtin_amdgcn_permlane32_swap(p[4], p[6], false, false);
    auto r57 = __builtin_amdgcn_permlane32_swap(p[5], p[7], false, false);
    b1.w[0] = r02[0]; b1.w[1] = r13[0]; b1.w[2] = r02[1]; b1.w[3] = r13[1];
    b2.w[0] = r46[0]; b2.w[1] = r57[0]; b2.w[2] = r46[1]; b2.w[3] = r57[1];
}

#define MFMA(a, b, c) __builtin_amdgcn_mfma_f32_32x32x16_bf16((a), (b), (c), 0, 0, 0)

// ---- hi/lo split fragments of a symmetric matrix in C/D layout.
struct SplitM { FB h1, h2, l1, l2; };

__device__ __forceinline__ void splitB(const f32x16& d, SplitM& s) {
    unsigned int ph[8], pl[8];
#pragma unroll
    for (int g = 0; g < 8; ++g) {
        float a = d[2 * g], b = d[2 * g + 1];
        ph[g] = pk2(a, b);
        pl[g] = pk2(a - rhi(a), b - rhi(b));
    }
    auto h02 = __builtin_amdgcn_permlane32_swap(ph[0], ph[2], false, false);
    auto h13 = __builtin_amdgcn_permlane32_swap(ph[1], ph[3], false, false);
    auto h46 = __builtin_amdgcn_permlane32_swap(ph[4], ph[6], false, false);
    auto h57 = __builtin_amdgcn_permlane32_swap(ph[5], ph[7], false, false);
    s.h1.w[0] = h02[0]; s.h1.w[1] = h13[0]; s.h1.w[2] = h02[1]; s.h1.w[3] = h13[1];
    s.h2.w[0] = h46[0]; s.h2.w[1] = h57[0]; s.h2.w[2] = h46[1]; s.h2.w[3] = h57[1];
    auto l02 = __builtin_amdgcn_permlane32_swap(pl[0], pl[2], false, false);
    auto l13 = __builtin_amdgcn_permlane32_swap(pl[1], pl[3], false, false);
    auto l46 = __builtin_amdgcn_permlane32_swap(pl[4], pl[6], false, false);
    auto l57 = __builtin_amdgcn_permlane32_swap(pl[5], pl[7], false, false);
    s.l1.w[0] = l02[0]; s.l1.w[1] = l13[0]; s.l1.w[2] = l02[1]; s.l1.w[3] = l13[1];
    s.l2.w[0] = l46[0]; s.l2.w[1] = l57[0]; s.l2.w[2] = l46[1]; s.l2.w[3] = l57[1];
}

// D = A*B for split operands; A must be symmetric (A-frags == its toB frags).
__device__ __forceinline__ f32x16 mulSS(const SplitM& A, const SplitM& B) {
    f32x16 d;
#pragma unroll
    for (int r = 0; r < 16; ++r) d[r] = 0.f;
    d = MFMA(A.h2.v, B.l2.v, d); d = MFMA(A.h1.v, B.l1.v, d);
    d = MFMA(A.l2.v, B.h2.v, d); d = MFMA(A.l1.v, B.h1.v, d);
    d = MFMA(A.h2.v, B.h2.v, d); d = MFMA(A.h1.v, B.h1.v, d);
    return d;
}

__device__ __forceinline__ float wred(float v) {   // 64-lane sum, broadcast
    v += __shfl_xor(v, 32);
    v += __shfl_xor(v, 16);
    v += __shfl_xor(v, 8);
    v += __shfl_xor(v, 4);
    v += __shfl_xor(v, 2);
    v += __shfl_xor(v, 1);
    return v;
}

// ---------------- block-level 32x32 matmul on LDS (row-major), 256 threads ----------------
__device__ __forceinline__ void mm32(const float* A, const float* B, float* D, int t) {
    int i = t >> 3, j0 = (t & 7) * 4;
    float a[32];
#pragma unroll
    for (int q = 0; q < 8; ++q) {
        float4 v = *(const float4*)&A[i * 32 + q * 4];
        a[4 * q] = v.x; a[4 * q + 1] = v.y; a[4 * q + 2] = v.z; a[4 * q + 3] = v.w;
    }
    float ax = 0.f, ay = 0.f, az = 0.f, aw = 0.f;
#pragma unroll
    for (int k = 0; k < 32; ++k) {
        float4 bv = *(const float4*)&B[k * 32 + j0];
        ax += a[k] * bv.x; ay += a[k] * bv.y; az += a[k] * bv.z; aw += a[k] * bv.w;
    }
    float4 r = { ax, ay, az, aw };
    *(float4*)&D[i * 32 + j0] = r;
}

// ---------------- K1: partial sums (256 blocks x 64 matrices) ----------------
__global__ __launch_bounds__(256) void k_psum(const float4* __restrict__ X4,
                                              float4* __restrict__ pA4) {
    int b = blockIdx.x, t = threadIdx.x;
    float4 acc = { 0.f, 0.f, 0.f, 0.f };
    for (int r = 0; r < 64; ++r) {
        float4 v = X4[(size_t)(b * 64 + r) * 256 + t];
        acc.x += v.x; acc.y += v.y; acc.z += v.z; acc.w += v.w;
    }
    pA4[b * 256 + t] = acc;
}

// ---------------- K2: finalize G, G^{1/2}, G^{-1/2} ----------------
__global__ __launch_bounds__(256) void k_setup(const float4* __restrict__ pA4,
                                               float* __restrict__ ws) {
    __shared__ alignas(16) float sG[1024], sE[1024], sPa[1024], sPb[1024], sS1[1024], sS2[1024];
    __shared__ float sc[2];
    int t = threadIdx.x;
    float4 acc = { 0.f, 0.f, 0.f, 0.f };
    for (int b = 0; b < 256; ++b) {
        float4 v = pA4[b * 256 + t];
        acc.x += v.x; acc.y += v.y; acc.z += v.z; acc.w += v.w;
    }
    const float invM = 1.0f / (float)NMAT;
    sG[4 * t + 0] = acc.x * invM; sG[4 * t + 1] = acc.y * invM;
    sG[4 * t + 2] = acc.z * invM; sG[4 * t + 3] = acc.w * invM;
    __syncthreads();
    if (t == 0) { float s = 0.f; for (int d = 0; d < 32; ++d) s += sG[d * 33]; sc[0] = s / 32.0f; }
    __syncthreads();
    float c = sc[0];
    int i = t >> 3, j0 = (t & 7) * 4;
#pragma unroll
    for (int q = 0; q < 4; ++q) {
        int e = i * 32 + j0 + q;
        sE[e] = sG[e] / c - ((i == j0 + q) ? 1.f : 0.f);
    }
    __syncthreads();
    const float alp[9] = { 1.f, 0.5f, -0.125f, 0.0625f, -0.0390625f, 0.02734375f,
                           -0.0205078125f, 0.01611328125f, -0.013092041015625f };
    const float bet[9] = { 1.f, -0.5f, 0.375f, -0.3125f, 0.2734375f, -0.24609375f,
                           0.2255859375f, -0.20947265625f, 0.196380615234375f };
#pragma unroll
    for (int q = 0; q < 4; ++q) {
        int e = i * 32 + j0 + q;
        float d = (i == j0 + q) ? 1.f : 0.f;
        sS1[e] = d + alp[1] * sE[e];
        sS2[e] = d + bet[1] * sE[e];
        sPa[e] = sE[e];
    }
    __syncthreads();
    {
        float* P = sPa; float* Pn = sPb;
        for (int k = 2; k <= 8; ++k) {
            mm32(P, sE, Pn, t);
            __syncthreads();
#pragma unroll
            for (int q = 0; q < 4; ++q) {
                int e = i * 32 + j0 + q;
                sS1[e] += alp[k] * Pn[e];
                sS2[e] += bet[k] * Pn[e];
            }
            float* tmp = P; P = Pn; Pn = tmp;
            __syncthreads();
        }
    }
    float rc = sqrtf(c);
#pragma unroll
    for (int q = 0; q < 4; ++q) {
        int e = i * 32 + j0 + q;
        ws[WS_GSQ + e] = rc * sS1[e];
        ws[WS_GQ + e]  = sS2[e] / rc;
    }
}

// ---------------- K3: sum of matrix logs, dual-chain MFMA Clenshaw ----------------
// Each wave owns matrices m0 and m0+NWAVES and runs BOTH Clenshaw chains
// concurrently (independent dependency chains -> ILP fills MFMA/VALU stalls).
__global__ __launch_bounds__(256, 2) void k_logsum(const float* __restrict__ Xg,
                                                   const float* __restrict__ ws,
                                                   float* __restrict__ pL) {
    __shared__ float sLacc[1024];
    __shared__ float scheb[NCOEF];
    int t = threadIdx.x;
    for (int e = t; e < 1024; e += 256) sLacc[e] = 0.f;
    if (t < NCOEF) {
        // closed-form Chebyshev coeffs of log on [a,b]
        float alpha = 0.5f * (float)(CHEB_A + CHEB_B);
        float beta  = 0.5f * (float)(CHEB_B - CHEB_A);
        float dd = beta / alpha, s = sqrtf(1.f - dd * dd), tt = dd / (1.f + s);
        float v;
        if (t == 0) v = 2.f * (logf(alpha) + logf(0.5f * (1.f + s)));
        else        v = 2.f * ((t & 1) ? 1.f : -1.f) * exp2f((float)t * log2f(tt)) / (float)t;
        scheb[t] = v;
    }
    const int wv = t >> 6, lane = t & 63, h = lane >> 5, col = lane & 31;

    // diagonal mask in C/D layout: row(reg)=(reg&3)+8*(reg>>2)+4h == col
    int hasd = (((col >> 2) & 1) == h);
    int dreg = 4 * (col >> 3) + (col & 3);
    f32x16 dm;
#pragma unroll
    for (int r = 0; r < 16; ++r) dm[r] = (hasd && r == dreg) ? 1.f : 0.f;

    // Gq fragments (symmetric; same regs serve as A- and B-operand), hi/lo split
    const float* Gqp = ws + WS_GQ + col * 32 + 8 * h;
    float4 ga = *(const float4*)(Gqp);
    float4 gb = *(const float4*)(Gqp + 4);
    float4 gc = *(const float4*)(Gqp + 16);
    float4 gd = *(const float4*)(Gqp + 20);
    FB GqH1, GqH2, GqL1, GqL2;
    GqH1.w[0] = pk2(ga.x, ga.y); GqH1.w[1] = pk2(ga.z, ga.w);
    GqH1.w[2] = pk2(gb.x, gb.y); GqH1.w[3] = pk2(gb.z, gb.w);
    GqH2.w[0] = pk2(gc.x, gc.y); GqH2.w[1] = pk2(gc.z, gc.w);
    GqH2.w[2] = pk2(gd.x, gd.y); GqH2.w[3] = pk2(gd.z, gd.w);
    GqL1.w[0] = pk2(ga.x - rhi(ga.x), ga.y - rhi(ga.y));
    GqL1.w[1] = pk2(ga.z - rhi(ga.z), ga.w - rhi(ga.w));
    GqL1.w[2] = pk2(gb.x - rhi(gb.x), gb.y - rhi(gb.y));
    GqL1.w[3] = pk2(gb.z - rhi(gb.z), gb.w - rhi(gb.w));
    GqL2.w[0] = pk2(gc.x - rhi(gc.x), gc.y - rhi(gc.y));
    GqL2.w[1] = pk2(gc.z - rhi(gc.z), gc.w - rhi(gc.w));
    GqL2.w[2] = pk2(gd.x - rhi(gd.x), gd.y - rhi(gd.y));
    GqL2.w[3] = pk2(gd.z - rhi(gd.z), gd.w - rhi(gd.w));
    __syncthreads();   // scheb + sLacc ready

    const float m2v = 2.0f / (float)(CHEB_B - CHEB_A);
    const float shv = (float)((CHEB_A + CHEB_B) / (CHEB_B - CHEB_A));
    const float tm = 2.f * m2v, tsh = -2.f * shv;
    const float cDv = scheb[DDEG], c0h = 0.5f * scheb[0];

    // constant cD*I Clenshaw-seed B-fragments (matrix-independent -> hoisted)
    FB CDB1, CDB2;
    {
        f32x16 cDdm;
#pragma unroll
        for (int r = 0; r < 16; ++r) cDdm[r] = cDv * dm[r];
        toB<false>(cDdm, CDB1, CDB2);
    }

    const int m0 = blockIdx.x * 4 + wv;
    const int m1 = m0 + NWAVES;

    // ---- load + pack both matrices up front (latency hidden under U/S work)
    const float* Xma = Xg + (size_t)m0 * 1024 + col * 32 + 8 * h;
    const float* Xmb = Xg + (size_t)m1 * 1024 + col * 32 + 8 * h;
    float4 a0 = *(const float4*)(Xma);
    float4 a1 = *(const float4*)(Xma + 4);
    float4 a2 = *(const float4*)(Xma + 16);
    float4 a3 = *(const float4*)(Xma + 20);
    float4 b0 = *(const float4*)(Xmb);
    float4 b1v = *(const float4*)(Xmb + 4);
    float4 b2v = *(const float4*)(Xmb + 16);
    float4 b3v = *(const float4*)(Xmb + 20);
    FB AXa1, AXa2, AXb1, AXb2;
    AXa1.w[0] = cvt2(a0.x, a0.y); AXa1.w[1] = cvt2(a0.z, a0.w);
    AXa1.w[2] = cvt2(a1.x, a1.y); AXa1.w[3] = cvt2(a1.z, a1.w);
    AXa2.w[0] = cvt2(a2.x, a2.y); AXa2.w[1] = cvt2(a2.z, a2.w);
    AXa2.w[2] = cvt2(a3.x, a3.y); AXa2.w[3] = cvt2(a3.z, a3.w);
    AXb1.w[0] = cvt2(b0.x, b0.y); AXb1.w[1] = cvt2(b0.z, b0.w);
    AXb1.w[2] = cvt2(b1v.x, b1v.y); AXb1.w[3] = cvt2(b1v.z, b1v.w);
    AXb2.w[0] = cvt2(b2v.x, b2v.y); AXb2.w[1] = cvt2(b2v.z, b2v.w);
    AXb2.w[2] = cvt2(b3v.x, b3v.y); AXb2.w[3] = cvt2(b3v.z, b3v.w);

    // ---- U = X * Gq (both chains)
    f32x16 Ua, Ub;
#pragma unroll
    for (int r = 0; r < 16; ++r) { Ua[r] = 0.f; Ub[r] = 0.f; }
    Ua = MFMA(AXa2.v, GqL2.v, Ua); Ub = MFMA(AXb2.v, GqL2.v, Ub);
    Ua = MFMA(AXa1.v, GqL1.v, Ua); Ub = MFMA(AXb1.v, GqL1.v, Ub);
    Ua = MFMA(AXa2.v, GqH2.v, Ua); Ub = MFMA(AXb2.v, GqH2.v, Ub);
    Ua = MFMA(AXa1.v, GqH1.v, Ua); Ub = MFMA(AXb1.v, GqH1.v, Ub);
    FB Ba1, Ba2, Bb1, Bb2;
    toB<false>(Ua, Ba1, Ba2);
    toB<false>(Ub, Bb1, Bb2);
    // ---- S = Gq * U
    f32x16 Sa, Sb;
#pragma unroll
    for (int r = 0; r < 16; ++r) { Sa[r] = 0.f; Sb[r] = 0.f; }
    Sa = MFMA(GqL2.v, Ba2.v, Sa); Sb = MFMA(GqL2.v, Bb2.v, Sb);
    Sa = MFMA(GqL1.v, Ba1.v, Sa); Sb = MFMA(GqL1.v, Bb1.v, Sb);
    Sa = MFMA(GqH2.v, Ba2.v, Sa); Sb = MFMA(GqH2.v, Bb2.v, Sb);
    Sa = MFMA(GqH1.v, Ba1.v, Sa); Sb = MFMA(GqH1.v, Bb1.v, Sb);
    // ---- 2*Shat = tm*S + tsh*I -> A-operand frags (symmetric)
    f32x16 Ta, Tb;
#pragma unroll
    for (int r = 0; r < 16; ++r) {
        Ta[r] = fmaf(tm, Sa[r], tsh * dm[r]);
        Tb[r] = fmaf(tm, Sb[r], tsh * dm[r]);
    }
    FB Aa1, Aa2, Ab1, Ab2;
    toB<false>(Ta, Aa1, Aa2);
    toB<false>(Tb, Ab1, Ab2);

    // ---- Clenshaw: b_k = c_k I - b_{k+2} + (2Shat)*b_{k+1}, both chains
    f32x16 X0a, X1a, X0b, X1b;
#pragma unroll
    for (int r = 0; r < 16; ++r) {
        X1a[r] = cDv * dm[r]; X0a[r] = 0.f;
        X1b[r] = cDv * dm[r]; X0b[r] = 0.f;
    }
    Ba1 = CDB1; Ba2 = CDB2; Bb1 = CDB1; Bb2 = CDB2;
    for (int it = 0; it < NITER; ++it) {
        float ka = scheb[DDEG - 1 - 2 * it];
        float kb = scheb[DDEG - 2 - 2 * it];
#pragma unroll
        for (int r = 0; r < 16; ++r) {
            X0a[r] = fmaf(ka, dm[r], -X0a[r]);
            X0b[r] = fmaf(ka, dm[r], -X0b[r]);
        }
        X0a = MFMA(Aa2.v, Ba2.v, X0a); X0b = MFMA(Ab2.v, Bb2.v, X0b);
        X0a = MFMA(Aa1.v, Ba1.v, X0a); X0b = MFMA(Ab1.v, Bb1.v, X0b);
        toB<false>(X0a, Ba1, Ba2);
        toB<false>(X0b, Bb1, Bb2);
#pragma unroll
        for (int r = 0; r < 16; ++r) {
            X1a[r] = fmaf(kb, dm[r], -X1a[r]);
            X1b[r] = fmaf(kb, dm[r], -X1b[r]);
        }
        X1a = MFMA(Aa2.v, Ba2.v, X1a); X1b = MFMA(Ab2.v, Bb2.v, X1b);
        X1a = MFMA(Aa1.v, Ba1.v, X1a); X1b = MFMA(Ab1.v, Bb1.v, X1b);
        if (it < NITER - 1) {
            toB<false>(X1a, Ba1, Ba2);
            toB<false>(X1b, Bb1, Bb2);
        } else {
            toB<true>(X1a, Ba1, Ba2);   // 0.5*b_1
            toB<true>(X1b, Bb1, Bb2);
        }
    }
    // ---- f = 0.5*c0 I - b_2 + (2Shat)*(0.5 b_1)
#pragma unroll
    for (int r = 0; r < 16; ++r) {
        X0a[r] = fmaf(c0h, dm[r], -X0a[r]);
        X0b[r] = fmaf(c0h, dm[r], -X0b[r]);
    }
    X0a = MFMA(Aa2.v, Ba2.v, X0a); X0b = MFMA(Ab2.v, Bb2.v, X0b);
    X0a = MFMA(Aa1.v, Ba1.v, X0a); X0b = MFMA(Ab1.v, Bb1.v, X0b);

    f32x16 Facc;
#pragma unroll
    for (int r = 0; r < 16; ++r) Facc[r] = X0a[r] + X0b[r];

#pragma unroll
    for (int r = 0; r < 16; ++r) {
        int row = (r & 3) + 8 * (r >> 2) + 4 * h;
        atomicAdd(&sLacc[row * 32 + col], Facc[r]);
    }
    __syncthreads();
    float4 v = *(float4*)&sLacc[4 * t];
    ((float4*)pL)[(size_t)blockIdx.x * 256 + t] = v;
}

// ---------------- K3b: reduce 2048 partials -> 32 ----------------
__global__ __launch_bounds__(256) void k_red32(const float4* __restrict__ pL4,
                                               float4* __restrict__ pL24) {
    int b = blockIdx.x, t = threadIdx.x;
    float4 acc = { 0.f, 0.f, 0.f, 0.f };
    for (int r = 0; r < 64; ++r) {
        float4 v = pL4[(size_t)(b * 64 + r) * 256 + t];
        acc.x += v.x; acc.y += v.y; acc.z += v.z; acc.w += v.w;
    }
    pL24[b * 256 + t] = acc;
}

// ---------------- K4: single-wave MFMA chain: L -> expL -> Gn -> Gn^{-1/2};
//                  W^{1/2}; C = Wsq*Gn_isq. ----------------
__global__ __launch_bounds__(256) void k_final(const float4* __restrict__ pL24,
                                               const float* __restrict__ Wg,
                                               float* __restrict__ ws) {
    __shared__ alignas(16) float sL[1024];
    int t = threadIdx.x;
    // stage: all 256 threads reduce the 32 partials
    {
        float4 acc = { 0.f, 0.f, 0.f, 0.f };
        for (int b = 0; b < 32; ++b) {
            float4 v = pL24[b * 256 + t];
            acc.x += v.x; acc.y += v.y; acc.z += v.z; acc.w += v.w;
        }
        const float invM = 1.0f / (float)NMAT;
        sL[4 * t + 0] = acc.x * invM; sL[4 * t + 1] = acc.y * invM;
        sL[4 * t + 2] = acc.z * invM; sL[4 * t + 3] = acc.w * invM;
    }
    __syncthreads();
    if (t >= 64) return;          // wave 0 only from here (no more barriers)

    const int h = t >> 5, col = t & 31;
    const int hasd = (((col >> 2) & 1) == h);
    const int dreg = 4 * (col >> 3) + (col & 3);
    f32x16 dm;
#pragma unroll
    for (int r = 0; r < 16; ++r) dm[r] = (hasd && r == dreg) ? 1.f : 0.f;

    // mean-L into C/D registers
    f32x16 Lm;
#pragma unroll
    for (int r = 0; r < 16; ++r) Lm[r] = sL[ROWOF(r, h) * 32 + col];

    // s0 = tr(L)/32
    float tr = 0.f;
#pragma unroll
    for (int r = 0; r < 16; ++r) tr = fmaf(Lm[r], dm[r], tr);
    float s0 = wred(tr) / 32.0f;

    f32x16 L0;
#pragma unroll
    for (int r = 0; r < 16; ++r) L0[r] = fmaf(-s0, dm[r], Lm[r]);

    // expm series: E4 = sum_{k=0}^{12} L0^k/k!
    SplitM SL0; splitB(L0, SL0);
    f32x16 E4;
#pragma unroll
    for (int r = 0; r < 16; ++r) E4[r] = dm[r] + L0[r];
    SplitM SP = SL0;
    for (int k = 2; k <= 12; ++k) {
        f32x16 Pn = mulSS(SP, SL0);        // P * L0 (A=P symmetric)
        float invk = 1.0f / (float)k;
#pragma unroll
        for (int r = 0; r < 16; ++r) { Pn[r] *= invk; E4[r] += Pn[r]; }
        if (k < 12) splitB(Pn, SP);
    }
    float es = expf(s0);
#pragma unroll
    for (int r = 0; r < 16; ++r) E4[r] *= es;   // expL

    // Gn = Gsq * (expL * Gsq)
    f32x16 Gs;
#pragma unroll
    for (int r = 0; r < 16; ++r) Gs[r] = ws[WS_GSQ + ROWOF(r, h) * 32 + col];
    SplitM SG; splitB(Gs, SG);
    SplitM SE; splitB(E4, SE);
    f32x16 Mx = mulSS(SE, SG);              // expL*Gsq (A=expL sym; Mx NOT sym)
    SplitM SM; splitB(Mx, SM);
    f32x16 Gn = mulSS(SG, SM);              // A=Gsq sym, B=Mx

    // c2 = tr(Gn)/32; coupled NS x8 for (Gn/c2)^{-1/2}
    float tr2 = 0.f;
#pragma unroll
    for (int r = 0; r < 16; ++r) tr2 = fmaf(Gn[r], dm[r], tr2);
    float c2 = wred(tr2) / 32.0f;
    float ic2 = 1.0f / c2;

    f32x16 YC, ZC;
#pragma unroll
    for (int r = 0; r < 16; ++r) { YC[r] = Gn[r] * ic2; ZC[r] = dm[r]; }
    SplitM SY, SZ, ST;
    splitB(YC, SY); splitB(ZC, SZ);
    for (int it = 0; it < 8; ++it) {
        f32x16 ZY = mulSS(SZ, SY);          // Z*Y (Z sym)
        f32x16 T;
#pragma unroll
        for (int r = 0; r < 16; ++r) T[r] = fmaf(1.5f, dm[r], -0.5f * ZY[r]);
        splitB(T, ST);
        f32x16 Yn = mulSS(SY, ST);          // Y*T (Y sym)
        f32x16 Zn = mulSS(ST, SZ);          // T*Z (T sym)
        YC = Yn; ZC = Zn;
        splitB(YC, SY); splitB(ZC, SZ);
    }
    float rc2 = rsqrtf(c2);
    f32x16 Gi;
#pragma unroll
    for (int r = 0; r < 16; ++r) Gi[r] = ZC[r] * rc2;   // Gn^{-1/2}
    SplitM SGi; splitB(Gi, SGi);

    // W^{1/2}: c3 = ||W||_F; NS x15
    f32x16 Wm;
#pragma unroll
    for (int r = 0; r < 16; ++r) Wm[r] = Wg[ROWOF(r, h) * 32 + col];
    float ss = 0.f;
#pragma unroll
    for (int r = 0; r < 16; ++r) ss = fmaf(Wm[r], Wm[r], ss);
    float c3 = sqrtf(wred(ss));
    float ic3 = 1.0f / c3;
#pragma unroll
    for (int r = 0; r < 16; ++r) { YC[r] = Wm[r] * ic3; ZC[r] = dm[r]; }
    splitB(YC, SY); splitB(ZC, SZ);
    for (int it = 0; it < 15; ++it) {
        f32x16 ZY = mulSS(SZ, SY);
        f32x16 T;
#pragma unroll
        for (int r = 0; r < 16; ++r) T[r] = fmaf(1.5f, dm[r], -0.5f * ZY[r]);
        splitB(T, ST);
        f32x16 Yn = mulSS(SY, ST);
        f32x16 Zn = mulSS(ST, SZ);
        YC = Yn; ZC = Zn;
        splitB(YC, SY); splitB(ZC, SZ);
    }
    float rc3 = sqrtf(c3);
    f32x16 Ws;
#pragma unroll
    for (int r = 0; r < 16; ++r) Ws[r] = YC[r] * rc3;   // W^{1/2}
    SplitM SW; splitB(Ws, SW);

    f32x16 C = mulSS(SW, SGi);              // C = Wsq * Gn_isq (Wsq sym)
#pragma unroll
    for (int r = 0; r < 16; ++r) {
        int row = ROWOF(r, h);
        ws[WS_C + row * 32 + col] = C[r];
        ws[WS_CT + col * 32 + row] = C[r];
    }
}

// ---------------- K5: out = C * X * C^T ----------------
__global__ __launch_bounds__(256) void k_out(const float* __restrict__ Xg,
                                             const float* __restrict__ ws,
                                             float* __restrict__ Og) {
    __shared__ alignas(16) float sCT[1024];
    __shared__ alignas(16) float sX[1024];
    __shared__ alignas(16) float sTt[33 * 32];
    int t = threadIdx.x;
    int i = t >> 3, j0 = (t & 7) * 4;
    for (int e = t; e < 1024; e += 256) sCT[e] = ws[WS_CT + e];
    __syncthreads();
    for (int r = 0; r < 8; ++r) {
        int m = blockIdx.x * 8 + r;
        const float4* Xm4 = (const float4*)(Xg + (size_t)m * 1024);
        *(float4*)&sX[4 * t] = Xm4[t];
        __syncthreads();
        float ax = 0.f, ay = 0.f, az = 0.f, aw = 0.f;
#pragma unroll
        for (int k = 0; k < 32; ++k) {
            float cv = sCT[k * 32 + i];
            float4 xv = *(const float4*)&sX[k * 32 + j0];
            ax += cv * xv.x; ay += cv * xv.y; az += cv * xv.z; aw += cv * xv.w;
        }
        sTt[(j0 + 0) * 33 + i] = ax; sTt[(j0 + 1) * 33 + i] = ay;
        sTt[(j0 + 2) * 33 + i] = az; sTt[(j0 + 3) * 33 + i] = aw;
        __syncthreads();
        ax = ay = az = aw = 0.f;
#pragma unroll
        for (int k = 0; k < 32; ++k) {
            float tv = sTt[k * 33 + i];
            float4 cv = *(const float4*)&sCT[k * 32 + j0];
            ax += tv * cv.x; ay += tv * cv.y; az += tv * cv.z; aw += tv * cv.w;
        }
        float4 r4 = { ax, ay, az, aw };
        *(float4*)&Og[(size_t)m * 1024 + i * 32 + j0] = r4;
        __syncthreads();
    }
}

extern "C" void kernel_launch(void* const* d_in, const int* in_sizes, int n_in,
                              void* d_out, int out_size, void* d_ws, size_t ws_size,
                              hipStream_t stream) {
    const float* X = (const float*)d_in[0];
    const float* W = (const float*)d_in[1];
    float* out = (float*)d_out;
    float* ws  = (float*)d_ws;
    float* pA  = out + OUT_PA;
    float* pL  = out + OUT_PL;
    float* pL2 = out + OUT_PL2;

    hipLaunchKernelGGL(k_psum,   dim3(256),     dim3(256), 0, stream, (const float4*)X, (float4*)pA);
    hipLaunchKernelGGL(k_setup,  dim3(1),       dim3(256), 0, stream, (const float4*)pA, ws);
    hipLaunchKernelGGL(k_logsum, dim3(NLOGBLK), dim3(256), 0, stream, X, ws, pL);
    hipLaunchKernelGGL(k_red32,  dim3(32),      dim3(256), 0, stream, (const float4*)pL, (float4*)pL2);
    hipLaunchKernelGGL(k_final,  dim3(1),       dim3(256), 0, stream, (const float4*)pL2, W, ws);
    hipLaunchKernelGGL(k_out,    dim3(2048),    dim3(256), 0, stream, X, ws, out);
}

// Round 8
// 250.128 us; speedup vs baseline: 1.4381x; 1.1217x over previous
//
#include <hip/hip_runtime.h>
#include <math.h>

#define NMAT   16384
#define CHEB_A 0.08
#define CHEB_B 7.0
#define DDEG   29            // Chebyshev degree (odd); truncation tail ~5e-4 on [a,b]
#define NCOEF  (DDEG + 1)
#define NITER  ((DDEG - 1) / 2)   // Clenshaw pair-iterations
#define NLOGBLK 2048         // k_logsum blocks
#define NWAVES (NLOGBLK * 4) // 8192 waves; each wave owns matrices m0 and m0+NWAVES
#define NOUTBLK 1024         // k_out blocks
#define NOUTWV  (NOUTBLK * 4)

// ws float layout
#define WS_GQ    0
#define WS_GSQ   1024
#define WS_C     2112
#define WS_CT    3136

// d_out float scratch layout (consumed before final kernel overwrites):
#define OUT_PA   0          // 256*1024  (stage-1 partial sums of X)
#define OUT_PL   262144     // 2048*1024 (stage-3 partial sums of log)
#define OUT_PL2  2359296    // 32*1024

typedef __attribute__((ext_vector_type(8)))  short short8;   // 8 bf16 (4 VGPRs)
typedef __attribute__((ext_vector_type(16))) float f32x16;   // MFMA 32x32 C/D
typedef __attribute__((ext_vector_type(2)))  float f32x2;
typedef __attribute__((ext_vector_type(2)))  __bf16 bf16x2;

union FB { short8 v; unsigned int w[4]; };

// row of C/D-layout register r for half h: (r&3) + 8*(r>>2) + 4*h
#define ROWOF(r, h) (((r) & 3) + 8 * ((r) >> 2) + 4 * (h))

// round-half-up f32->bf16, pack pair into one dword (lo=a, hi=b). Split-path
// (keeps hi/lo splits exactly consistent with rhi()).
__device__ __forceinline__ unsigned int pk2(float a, float b) {
    unsigned int au = __float_as_uint(a) + 0x8000u;
    unsigned int bu = __float_as_uint(b) + 0x8000u;
    return __builtin_amdgcn_perm(bu, au, 0x07060302u);
}
__device__ __forceinline__ float rhi(float x) {   // bf16-rounded value as float
    return __uint_as_float((__float_as_uint(x) + 0x8000u) & 0xffff0000u);
}

// hot-path pack: RNE pack of 2 f32 -> 2 bf16 (lo=a, hi=b), compiler-emitted
// (vector fptrunc; gfx950 backend selects v_cvt_pk_bf16_f32 itself).
__device__ __forceinline__ unsigned int cvt2(float a, float b) {
    f32x2 s; s.x = a; s.y = b;
    bf16x2 t = __builtin_convertvector(s, bf16x2);
    unsigned int r;
    __builtin_memcpy(&r, &t, 4);
    return r;
}

// D (C/D layout fp32) -> two B-operand k-half fragments, pure in-register.
// C/D layout is column-owned (lane holds col=lane&31, rows (r&3)+8*(r>>2)+4h);
// B layout is also column-owned (lane holds col, k=8h+e). The only data motion
// needed is a half-wave exchange lane <-> lane^32: v_permlane32_swap_b32.
template <bool HALF>
__device__ __forceinline__ void toB(const f32x16& d, FB& b1, FB& b2) {
    unsigned int p[8];
#pragma unroll
    for (int g = 0; g < 8; ++g) {
        float s0 = HALF ? 0.5f * d[2 * g]     : d[2 * g];
        float s1 = HALF ? 0.5f * d[2 * g + 1] : d[2 * g + 1];
        p[g] = cvt2(s0, s1);
    }
    auto r02 = __builtin_amdgcn_permlane32_swap(p[0], p[2], false, false);
    auto r13 = __builtin_amdgcn_permlane32_swap(p[1], p[3], false, false);
    auto r46 = __builtin_amdgcn_permlane32_swap(p[4], p[6], false, false);
    auto r57 = __builtin_amdgcn_permlane32_swap(p[5], p[7], false, false);
    b1.w[0] = r02[0]; b1.w[1] = r13[0]; b1.w[2] = r02[1]; b1.w[3] = r13[1];
    b2.w[0] = r46[0]; b2.w[1] = r57[0]; b2.w[2] = r46[1]; b2.w[3] = r57[1];
}

#define MFMA(a, b, c) __builtin_amdgcn_mfma_f32_32x32x16_bf16((a), (b), (c), 0, 0, 0)

// ---- hi/lo split fragments of a symmetric matrix in C/D layout.
struct SplitM { FB h1, h2, l1, l2; };

__device__ __forceinline__ void splitB(const f32x16& d, SplitM& s) {
    unsigned int ph[8], pl[8];
#pragma unroll
    for (int g = 0; g < 8; ++g) {
        float a = d[2 * g], b = d[2 * g + 1];
        ph[g] = pk2(a, b);
        pl[g] = pk2(a - rhi(a), b - rhi(b));
    }
    auto h02 = __builtin_amdgcn_permlane32_swap(ph[0], ph[2], false, false);
    auto h13 = __builtin_amdgcn_permlane32_swap(ph[1], ph[3], false, false);
    auto h46 = __builtin_amdgcn_permlane32_swap(ph[4], ph[6], false, false);
    auto h57 = __builtin_amdgcn_permlane32_swap(ph[5], ph[7], false, false);
    s.h1.w[0] = h02[0]; s.h1.w[1] = h13[0]; s.h1.w[2] = h02[1]; s.h1.w[3] = h13[1];
    s.h2.w[0] = h46[0]; s.h2.w[1] = h57[0]; s.h2.w[2] = h46[1]; s.h2.w[3] = h57[1];
    auto l02 = __builtin_amdgcn_permlane32_swap(pl[0], pl[2], false, false);
    auto l13 = __builtin_amdgcn_permlane32_swap(pl[1], pl[3], false, false);
    auto l46 = __builtin_amdgcn_permlane32_swap(pl[4], pl[6], false, false);
    auto l57 = __builtin_amdgcn_permlane32_swap(pl[5], pl[7], false, false);
    s.l1.w[0] = l02[0]; s.l1.w[1] = l13[0]; s.l1.w[2] = l02[1]; s.l1.w[3] = l13[1];
    s.l2.w[0] = l46[0]; s.l2.w[1] = l57[0]; s.l2.w[2] = l46[1]; s.l2.w[3] = l57[1];
}

// D = A*B for split operands. The fragment duality: a B-frag set of matrix M,
// fed as the A-operand, represents M^T. So A here must be either a symmetric
// matrix's frags, or the frags of (desired A)^T.
__device__ __forceinline__ f32x16 mulSS(const SplitM& A, const SplitM& B) {
    f32x16 d;
#pragma unroll
    for (int r = 0; r < 16; ++r) d[r] = 0.f;
    d = MFMA(A.h2.v, B.l2.v, d); d = MFMA(A.h1.v, B.l1.v, d);
    d = MFMA(A.l2.v, B.h2.v, d); d = MFMA(A.l1.v, B.h1.v, d);
    d = MFMA(A.h2.v, B.h2.v, d); d = MFMA(A.h1.v, B.h1.v, d);
    return d;
}

// build split frags directly from a row-major 32x32 global/ws tile, reading
// M[col][k] per lane (the Gq load pattern) -> B-frags of M without permlane.
__device__ __forceinline__ void loadSplit(const float* __restrict__ base,
                                          int col, int h, SplitM& s) {
    const float* p = base + col * 32 + 8 * h;
    float4 a = *(const float4*)(p);
    float4 b = *(const float4*)(p + 4);
    float4 c = *(const float4*)(p + 16);
    float4 d = *(const float4*)(p + 20);
    s.h1.w[0] = pk2(a.x, a.y); s.h1.w[1] = pk2(a.z, a.w);
    s.h1.w[2] = pk2(b.x, b.y); s.h1.w[3] = pk2(b.z, b.w);
    s.h2.w[0] = pk2(c.x, c.y); s.h2.w[1] = pk2(c.z, c.w);
    s.h2.w[2] = pk2(d.x, d.y); s.h2.w[3] = pk2(d.z, d.w);
    s.l1.w[0] = pk2(a.x - rhi(a.x), a.y - rhi(a.y));
    s.l1.w[1] = pk2(a.z - rhi(a.z), a.w - rhi(a.w));
    s.l1.w[2] = pk2(b.x - rhi(b.x), b.y - rhi(b.y));
    s.l1.w[3] = pk2(b.z - rhi(b.z), b.w - rhi(b.w));
    s.l2.w[0] = pk2(c.x - rhi(c.x), c.y - rhi(c.y));
    s.l2.w[1] = pk2(c.z - rhi(c.z), c.w - rhi(c.w));
    s.l2.w[2] = pk2(d.x - rhi(d.x), d.y - rhi(d.y));
    s.l2.w[3] = pk2(d.z - rhi(d.z), d.w - rhi(d.w));
}

__device__ __forceinline__ float wred(float v) {   // 64-lane sum, broadcast
    v += __shfl_xor(v, 32);
    v += __shfl_xor(v, 16);
    v += __shfl_xor(v, 8);
    v += __shfl_xor(v, 4);
    v += __shfl_xor(v, 2);
    v += __shfl_xor(v, 1);
    return v;
}

// ---------------- block-level 32x32 matmul on LDS (row-major), 256 threads ----------------
__device__ __forceinline__ void mm32(const float* A, const float* B, float* D, int t) {
    int i = t >> 3, j0 = (t & 7) * 4;
    float a[32];
#pragma unroll
    for (int q = 0; q < 8; ++q) {
        float4 v = *(const float4*)&A[i * 32 + q * 4];
        a[4 * q] = v.x; a[4 * q + 1] = v.y; a[4 * q + 2] = v.z; a[4 * q + 3] = v.w;
    }
    float ax = 0.f, ay = 0.f, az = 0.f, aw = 0.f;
#pragma unroll
    for (int k = 0; k < 32; ++k) {
        float4 bv = *(const float4*)&B[k * 32 + j0];
        ax += a[k] * bv.x; ay += a[k] * bv.y; az += a[k] * bv.z; aw += a[k] * bv.w;
    }
    float4 r = { ax, ay, az, aw };
    *(float4*)&D[i * 32 + j0] = r;
}

// ---------------- K1: partial sums (256 blocks x 64 matrices) ----------------
__global__ __launch_bounds__(256) void k_psum(const float4* __restrict__ X4,
                                              float4* __restrict__ pA4) {
    int b = blockIdx.x, t = threadIdx.x;
    float4 acc = { 0.f, 0.f, 0.f, 0.f };
    for (int r = 0; r < 64; ++r) {
        float4 v = X4[(size_t)(b * 64 + r) * 256 + t];
        acc.x += v.x; acc.y += v.y; acc.z += v.z; acc.w += v.w;
    }
    pA4[b * 256 + t] = acc;
}

// ---------------- K2: finalize G, G^{1/2}, G^{-1/2} ----------------
__global__ __launch_bounds__(256) void k_setup(const float4* __restrict__ pA4,
                                               float* __restrict__ ws) {
    __shared__ alignas(16) float sG[1024], sE[1024], sPa[1024], sPb[1024], sS1[1024], sS2[1024];
    __shared__ float sc[2];
    int t = threadIdx.x;
    float4 acc = { 0.f, 0.f, 0.f, 0.f };
    for (int b = 0; b < 256; ++b) {
        float4 v = pA4[b * 256 + t];
        acc.x += v.x; acc.y += v.y; acc.z += v.z; acc.w += v.w;
    }
    const float invM = 1.0f / (float)NMAT;
    sG[4 * t + 0] = acc.x * invM; sG[4 * t + 1] = acc.y * invM;
    sG[4 * t + 2] = acc.z * invM; sG[4 * t + 3] = acc.w * invM;
    __syncthreads();
    if (t == 0) { float s = 0.f; for (int d = 0; d < 32; ++d) s += sG[d * 33]; sc[0] = s / 32.0f; }
    __syncthreads();
    float c = sc[0];
    int i = t >> 3, j0 = (t & 7) * 4;
#pragma unroll
    for (int q = 0; q < 4; ++q) {
        int e = i * 32 + j0 + q;
        sE[e] = sG[e] / c - ((i == j0 + q) ? 1.f : 0.f);
    }
    __syncthreads();
    const float alp[9] = { 1.f, 0.5f, -0.125f, 0.0625f, -0.0390625f, 0.02734375f,
                           -0.0205078125f, 0.01611328125f, -0.013092041015625f };
    const float bet[9] = { 1.f, -0.5f, 0.375f, -0.3125f, 0.2734375f, -0.24609375f,
                           0.2255859375f, -0.20947265625f, 0.196380615234375f };
#pragma unroll
    for (int q = 0; q < 4; ++q) {
        int e = i * 32 + j0 + q;
        float d = (i == j0 + q) ? 1.f : 0.f;
        sS1[e] = d + alp[1] * sE[e];
        sS2[e] = d + bet[1] * sE[e];
        sPa[e] = sE[e];
    }
    __syncthreads();
    {
        float* P = sPa; float* Pn = sPb;
        for (int k = 2; k <= 8; ++k) {
            mm32(P, sE, Pn, t);
            __syncthreads();
#pragma unroll
            for (int q = 0; q < 4; ++q) {
                int e = i * 32 + j0 + q;
                sS1[e] += alp[k] * Pn[e];
                sS2[e] += bet[k] * Pn[e];
            }
            float* tmp = P; P = Pn; Pn = tmp;
            __syncthreads();
        }
    }
    float rc = sqrtf(c);
#pragma unroll
    for (int q = 0; q < 4; ++q) {
        int e = i * 32 + j0 + q;
        ws[WS_GSQ + e] = rc * sS1[e];
        ws[WS_GQ + e]  = sS2[e] / rc;
    }
}

// ---------------- K3: sum of matrix logs, dual-chain MFMA Clenshaw ----------------
// Each wave owns matrices m0 and m0+NWAVES and runs BOTH Clenshaw chains
// concurrently. min 3 waves/EU -> total regs <=~170 (live set ~125; spill
// tripwire = WRITE_SIZE ballooning past ~16 MB).
__global__ __launch_bounds__(256, 3) void k_logsum(const float* __restrict__ Xg,
                                                   const float* __restrict__ ws,
                                                   float* __restrict__ pL) {
    __shared__ float sLacc[1024];
    __shared__ float scheb[NCOEF];
    int t = threadIdx.x;
    for (int e = t; e < 1024; e += 256) sLacc[e] = 0.f;
    if (t < NCOEF) {
        // closed-form Chebyshev coeffs of log on [a,b]
        float alpha = 0.5f * (float)(CHEB_A + CHEB_B);
        float beta  = 0.5f * (float)(CHEB_B - CHEB_A);
        float dd = beta / alpha, s = sqrtf(1.f - dd * dd), tt = dd / (1.f + s);
        float v;
        if (t == 0) v = 2.f * (logf(alpha) + logf(0.5f * (1.f + s)));
        else        v = 2.f * ((t & 1) ? 1.f : -1.f) * exp2f((float)t * log2f(tt)) / (float)t;
        scheb[t] = v;
    }
    const int wv = t >> 6, lane = t & 63, h = lane >> 5, col = lane & 31;

    // diagonal mask in C/D layout: row(reg)=(reg&3)+8*(reg>>2)+4h == col
    int hasd = (((col >> 2) & 1) == h);
    int dreg = 4 * (col >> 3) + (col & 3);
    f32x16 dm;
#pragma unroll
    for (int r = 0; r < 16; ++r) dm[r] = (hasd && r == dreg) ? 1.f : 0.f;

    // Gq fragments (symmetric; same regs serve as A- and B-operand), hi/lo split
    FB GqH1, GqH2, GqL1, GqL2;
    {
        SplitM SGq;
        loadSplit(ws + WS_GQ, col, h, SGq);
        GqH1 = SGq.h1; GqH2 = SGq.h2; GqL1 = SGq.l1; GqL2 = SGq.l2;
    }
    __syncthreads();   // scheb + sLacc ready

    const float m2v = 2.0f / (float)(CHEB_B - CHEB_A);
    const float shv = (float)((CHEB_A + CHEB_B) / (CHEB_B - CHEB_A));
    const float tm = 2.f * m2v, tsh = -2.f * shv;
    const float cDv = scheb[DDEG], c0h = 0.5f * scheb[0];

    const int m0 = blockIdx.x * 4 + wv;
    const int m1 = m0 + NWAVES;

    // ---- load + pack both matrices up front (latency hidden under U/S work)
    const float* Xma = Xg + (size_t)m0 * 1024 + col * 32 + 8 * h;
    const float* Xmb = Xg + (size_t)m1 * 1024 + col * 32 + 8 * h;
    float4 a0 = *(const float4*)(Xma);
    float4 a1 = *(const float4*)(Xma + 4);
    float4 a2 = *(const float4*)(Xma + 16);
    float4 a3 = *(const float4*)(Xma + 20);
    float4 b0 = *(const float4*)(Xmb);
    float4 b1v = *(const float4*)(Xmb + 4);
    float4 b2v = *(const float4*)(Xmb + 16);
    float4 b3v = *(const float4*)(Xmb + 20);
    FB AXa1, AXa2, AXb1, AXb2;
    AXa1.w[0] = cvt2(a0.x, a0.y); AXa1.w[1] = cvt2(a0.z, a0.w);
    AXa1.w[2] = cvt2(a1.x, a1.y); AXa1.w[3] = cvt2(a1.z, a1.w);
    AXa2.w[0] = cvt2(a2.x, a2.y); AXa2.w[1] = cvt2(a2.z, a2.w);
    AXa2.w[2] = cvt2(a3.x, a3.y); AXa2.w[3] = cvt2(a3.z, a3.w);
    AXb1.w[0] = cvt2(b0.x, b0.y); AXb1.w[1] = cvt2(b0.z, b0.w);
    AXb1.w[2] = cvt2(b1v.x, b1v.y); AXb1.w[3] = cvt2(b1v.z, b1v.w);
    AXb2.w[0] = cvt2(b2v.x, b2v.y); AXb2.w[1] = cvt2(b2v.z, b2v.w);
    AXb2.w[2] = cvt2(b3v.x, b3v.y); AXb2.w[3] = cvt2(b3v.z, b3v.w);

    // ---- U = X * Gq (both chains)
    f32x16 Ua, Ub;
#pragma unroll
    for (int r = 0; r < 16; ++r) { Ua[r] = 0.f; Ub[r] = 0.f; }
    Ua = MFMA(AXa2.v, GqL2.v, Ua); Ub = MFMA(AXb2.v, GqL2.v, Ub);
    Ua = MFMA(AXa1.v, GqL1.v, Ua); Ub = MFMA(AXb1.v, GqL1.v, Ub);
    Ua = MFMA(AXa2.v, GqH2.v, Ua); Ub = MFMA(AXb2.v, GqH2.v, Ub);
    Ua = MFMA(AXa1.v, GqH1.v, Ua); Ub = MFMA(AXb1.v, GqH1.v, Ub);
    FB Ba1, Ba2, Bb1, Bb2;
    toB<false>(Ua, Ba1, Ba2);
    toB<false>(Ub, Bb1, Bb2);
    // ---- S = Gq * U
    f32x16 Sa, Sb;
#pragma unroll
    for (int r = 0; r < 16; ++r) { Sa[r] = 0.f; Sb[r] = 0.f; }
    Sa = MFMA(GqL2.v, Ba2.v, Sa); Sb = MFMA(GqL2.v, Bb2.v, Sb);
    Sa = MFMA(GqL1.v, Ba1.v, Sa); Sb = MFMA(GqL1.v, Bb1.v, Sb);
    Sa = MFMA(GqH2.v, Ba2.v, Sa); Sb = MFMA(GqH2.v, Bb2.v, Sb);
    Sa = MFMA(GqH1.v, Ba1.v, Sa); Sb = MFMA(GqH1.v, Bb1.v, Sb);
    // ---- 2*Shat = tm*S + tsh*I -> A-operand frags (symmetric)
    f32x16 Ta, Tb;
#pragma unroll
    for (int r = 0; r < 16; ++r) {
        Ta[r] = fmaf(tm, Sa[r], tsh * dm[r]);
        Tb[r] = fmaf(tm, Sb[r], tsh * dm[r]);
    }
    FB Aa1, Aa2, Ab1, Ab2;
    toB<false>(Ta, Aa1, Aa2);
    toB<false>(Tb, Ab1, Ab2);

    // ---- Clenshaw: b_k = c_k I - b_{k+2} + (2Shat)*b_{k+1}, both chains
    f32x16 X0a, X1a, X0b, X1b;
#pragma unroll
    for (int r = 0; r < 16; ++r) {
        X1a[r] = cDv * dm[r]; X0a[r] = 0.f;
        X1b[r] = cDv * dm[r]; X0b[r] = 0.f;
    }
    toB<false>(X1a, Ba1, Ba2);       // seed frags of cD*I (computed in place)
    Bb1 = Ba1; Bb2 = Ba2;
    for (int it = 0; it < NITER; ++it) {
        float ka = scheb[DDEG - 1 - 2 * it];
        float kb = scheb[DDEG - 2 - 2 * it];
#pragma unroll
        for (int r = 0; r < 16; ++r) {
            X0a[r] = fmaf(ka, dm[r], -X0a[r]);
            X0b[r] = fmaf(ka, dm[r], -X0b[r]);
        }
        X0a = MFMA(Aa2.v, Ba2.v, X0a); X0b = MFMA(Ab2.v, Bb2.v, X0b);
        X0a = MFMA(Aa1.v, Ba1.v, X0a); X0b = MFMA(Ab1.v, Bb1.v, X0b);
        toB<false>(X0a, Ba1, Ba2);
        toB<false>(X0b, Bb1, Bb2);
#pragma unroll
        for (int r = 0; r < 16; ++r) {
            X1a[r] = fmaf(kb, dm[r], -X1a[r]);
            X1b[r] = fmaf(kb, dm[r], -X1b[r]);
        }
        X1a = MFMA(Aa2.v, Ba2.v, X1a); X1b = MFMA(Ab2.v, Bb2.v, X1b);
        X1a = MFMA(Aa1.v, Ba1.v, X1a); X1b = MFMA(Ab1.v, Bb1.v, X1b);
        if (it < NITER - 1) {
            toB<false>(X1a, Ba1, Ba2);
            toB<false>(X1b, Bb1, Bb2);
        } else {
            toB<true>(X1a, Ba1, Ba2);   // 0.5*b_1
            toB<true>(X1b, Bb1, Bb2);
        }
    }
    // ---- f = 0.5*c0 I - b_2 + (2Shat)*(0.5 b_1)
#pragma unroll
    for (int r = 0; r < 16; ++r) {
        X0a[r] = fmaf(c0h, dm[r], -X0a[r]);
        X0b[r] = fmaf(c0h, dm[r], -X0b[r]);
    }
    X0a = MFMA(Aa2.v, Ba2.v, X0a); X0b = MFMA(Ab2.v, Bb2.v, X0b);
    X0a = MFMA(Aa1.v, Ba1.v, X0a); X0b = MFMA(Ab1.v, Bb1.v, X0b);

    f32x16 Facc;
#pragma unroll
    for (int r = 0; r < 16; ++r) Facc[r] = X0a[r] + X0b[r];

#pragma unroll
    for (int r = 0; r < 16; ++r) {
        int row = (r & 3) + 8 * (r >> 2) + 4 * h;
        atomicAdd(&sLacc[row * 32 + col], Facc[r]);
    }
    __syncthreads();
    float4 v = *(float4*)&sLacc[4 * t];
    ((float4*)pL)[(size_t)blockIdx.x * 256 + t] = v;
}

// ---------------- K3b: reduce 2048 partials -> 32 ----------------
__global__ __launch_bounds__(256) void k_red32(const float4* __restrict__ pL4,
                                               float4* __restrict__ pL24) {
    int b = blockIdx.x, t = threadIdx.x;
    float4 acc = { 0.f, 0.f, 0.f, 0.f };
    for (int r = 0; r < 64; ++r) {
        float4 v = pL4[(size_t)(b * 64 + r) * 256 + t];
        acc.x += v.x; acc.y += v.y; acc.z += v.z; acc.w += v.w;
    }
    pL24[b * 256 + t] = acc;
}

// ---------------- K4: single-wave MFMA chain: L -> expL -> Gn -> Gn^{-1/2};
//                  W^{1/2}; C = Wsq*Gn_isq. ----------------
__global__ __launch_bounds__(256) void k_final(const float4* __restrict__ pL24,
                                               const float* __restrict__ Wg,
                                               float* __restrict__ ws) {
    __shared__ alignas(16) float sL[1024];
    int t = threadIdx.x;
    // stage: all 256 threads reduce the 32 partials
    {
        float4 acc = { 0.f, 0.f, 0.f, 0.f };
        for (int b = 0; b < 32; ++b) {
            float4 v = pL24[b * 256 + t];
            acc.x += v.x; acc.y += v.y; acc.z += v.z; acc.w += v.w;
        }
        const float invM = 1.0f / (float)NMAT;
        sL[4 * t + 0] = acc.x * invM; sL[4 * t + 1] = acc.y * invM;
        sL[4 * t + 2] = acc.z * invM; sL[4 * t + 3] = acc.w * invM;
    }
    __syncthreads();
    if (t >= 64) return;          // wave 0 only from here (no more barriers)

    const int h = t >> 5, col = t & 31;
    const int hasd = (((col >> 2) & 1) == h);
    const int dreg = 4 * (col >> 3) + (col & 3);
    f32x16 dm;
#pragma unroll
    for (int r = 0; r < 16; ++r) dm[r] = (hasd && r == dreg) ? 1.f : 0.f;

    // mean-L into C/D registers
    f32x16 Lm;
#pragma unroll
    for (int r = 0; r < 16; ++r) Lm[r] = sL[ROWOF(r, h) * 32 + col];

    // s0 = tr(L)/32
    float tr = 0.f;
#pragma unroll
    for (int r = 0; r < 16; ++r) tr = fmaf(Lm[r], dm[r], tr);
    float s0 = wred(tr) / 32.0f;

    f32x16 L0;
#pragma unroll
    for (int r = 0; r < 16; ++r) L0[r] = fmaf(-s0, dm[r], Lm[r]);

    // expm series: E4 = sum_{k=0}^{12} L0^k/k!
    SplitM SL0; splitB(L0, SL0);
    f32x16 E4;
#pragma unroll
    for (int r = 0; r < 16; ++r) E4[r] = dm[r] + L0[r];
    SplitM SP = SL0;
    for (int k = 2; k <= 12; ++k) {
        f32x16 Pn = mulSS(SP, SL0);        // P * L0 (A=P symmetric)
        float invk = 1.0f / (float)k;
#pragma unroll
        for (int r = 0; r < 16; ++r) { Pn[r] *= invk; E4[r] += Pn[r]; }
        if (k < 12) splitB(Pn, SP);
    }
    float es = expf(s0);
#pragma unroll
    for (int r = 0; r < 16; ++r) E4[r] *= es;   // expL

    // Gn = Gsq * (expL * Gsq)
    f32x16 Gs;
#pragma unroll
    for (int r = 0; r < 16; ++r) Gs[r] = ws[WS_GSQ + ROWOF(r, h) * 32 + col];
    SplitM SG; splitB(Gs, SG);
    SplitM SE; splitB(E4, SE);
    f32x16 Mx = mulSS(SE, SG);              // expL*Gsq (A=expL sym; Mx NOT sym)
    SplitM SM; splitB(Mx, SM);
    f32x16 Gn = mulSS(SG, SM);              // A=Gsq sym, B=Mx

    // c2 = tr(Gn)/32; coupled NS x8 for (Gn/c2)^{-1/2}
    float tr2 = 0.f;
#pragma unroll
    for (int r = 0; r < 16; ++r) tr2 = fmaf(Gn[r], dm[r], tr2);
    float c2 = wred(tr2) / 32.0f;
    float ic2 = 1.0f / c2;

    f32x16 YC, ZC;
#pragma unroll
    for (int r = 0; r < 16; ++r) { YC[r] = Gn[r] * ic2; ZC[r] = dm[r]; }
    SplitM SY, SZ, ST;
    splitB(YC, SY); splitB(ZC, SZ);
    for (int it = 0; it < 8; ++it) {
        f32x16 ZY = mulSS(SZ, SY);          // Z*Y (Z sym)
        f32x16 T;
#pragma unroll
        for (int r = 0; r < 16; ++r) T[r] = fmaf(1.5f, dm[r], -0.5f * ZY[r]);
        splitB(T, ST);
        f32x16 Yn = mulSS(SY, ST);          // Y*T (Y sym)
        f32x16 Zn = mulSS(ST, SZ);          // T*Z (T sym)
        YC = Yn; ZC = Zn;
        splitB(YC, SY); splitB(ZC, SZ);
    }
    float rc2 = rsqrtf(c2);
    f32x16 Gi;
#pragma unroll
    for (int r = 0; r < 16; ++r) Gi[r] = ZC[r] * rc2;   // Gn^{-1/2}
    SplitM SGi; splitB(Gi, SGi);

    // W^{1/2}: c3 = ||W||_F; NS x15
    f32x16 Wm;
#pragma unroll
    for (int r = 0; r < 16; ++r) Wm[r] = Wg[ROWOF(r, h) * 32 + col];
    float ss = 0.f;
#pragma unroll
    for (int r = 0; r < 16; ++r) ss = fmaf(Wm[r], Wm[r], ss);
    float c3 = sqrtf(wred(ss));
    float ic3 = 1.0f / c3;
#pragma unroll
    for (int r = 0; r < 16; ++r) { YC[r] = Wm[r] * ic3; ZC[r] = dm[r]; }
    splitB(YC, SY); splitB(ZC, SZ);
    for (int it = 0; it < 15; ++it) {
        f32x16 ZY = mulSS(SZ, SY);
        f32x16 T;
#pragma unroll
        for (int r = 0; r < 16; ++r) T[r] = fmaf(1.5f, dm[r], -0.5f * ZY[r]);
        splitB(T, ST);
        f32x16 Yn = mulSS(SY, ST);
        f32x16 Zn = mulSS(ST, SZ);
        YC = Yn; ZC = Zn;
        splitB(YC, SY); splitB(ZC, SZ);
    }
    float rc3 = sqrtf(c3);
    f32x16 Ws;
#pragma unroll
    for (int r = 0; r < 16; ++r) Ws[r] = YC[r] * rc3;   // W^{1/2}
    SplitM SW; splitB(Ws, SW);

    f32x16 C = mulSS(SW, SGi);              // C = Wsq * Gn_isq (Wsq sym)
#pragma unroll
    for (int r = 0; r < 16; ++r) {
        int row = ROWOF(r, h);
        ws[WS_C + row * 32 + col] = C[r];
        ws[WS_CT + col * 32 + row] = C[r];
    }
}

// ---------------- K5: out = C * X * C^T via MFMA ----------------
// Fragment duality: B-frags of C^T (direct-loaded from WS_C: C^T[k][col] =
// C[col][k] = ws[WS_C + col*32 + k]) serve as (a) the B-operand for V = X*C^T
// and (b) the A-operand for out = C*V. X and V hi/lo-split (3-term products).
__global__ __launch_bounds__(256) void k_out(const float* __restrict__ Xg,
                                             const float* __restrict__ ws,
                                             float* __restrict__ Og) {
    int t = threadIdx.x;
    const int wv = t >> 6, lane = t & 63, h = lane >> 5, col = lane & 31;
    SplitM SCt;
    loadSplit(ws + WS_C, col, h, SCt);   // frags of C^T (constant per wave)

    for (int m = blockIdx.x * 4 + wv; m < NMAT; m += NOUTWV) {
        SplitM SX;
        loadSplit(Xg + (size_t)m * 1024, col, h, SX);   // frags of X (sym)
        f32x16 V = mulSS(SX, SCt);        // V = X * C^T  (A = X, symmetric)
        SplitM SV; splitB(V, SV);
        f32x16 O = mulSS(SCt, SV);        // out = C * V  (A-frags of C = SCt)
        float* Om = Og + (size_t)m * 1024;
#pragma unroll
        for (int r = 0; r < 16; ++r) {
            Om[ROWOF(r, h) * 32 + col] = O[r];
        }
    }
}

extern "C" void kernel_launch(void* const* d_in, const int* in_sizes, int n_in,
                              void* d_out, int out_size, void* d_ws, size_t ws_size,
                              hipStream_t stream) {
    const float* X = (const float*)d_in[0];
    const float* W = (const float*)d_in[1];
    float* out = (float*)d_out;
    float* ws  = (float*)d_ws;
    float* pA  = out + OUT_PA;
    float* pL  = out + OUT_PL;
    float* pL2 = out + OUT_PL2;

    hipLaunchKernelGGL(k_psum,   dim3(256),     dim3(256), 0, stream, (const float4*)X, (float4*)pA);
    hipLaunchKernelGGL(k_setup,  dim3(1),       dim3(256), 0, stream, (const float4*)pA, ws);
    hipLaunchKernelGGL(k_logsum, dim3(NLOGBLK), dim3(256), 0, stream, X, ws, pL);
    hipLaunchKernelGGL(k_red32,  dim3(32),      dim3(256), 0, stream, (const float4*)pL, (float4*)pL2);
    hipLaunchKernelGGL(k_final,  dim3(1),       dim3(256), 0, stream, (const float4*)pL2, W, ws);
    hipLaunchKernelGGL(k_out,    dim3(NOUTBLK), dim3(256), 0, stream, X, ws, out);
}

// Round 9
// 236.064 us; speedup vs baseline: 1.5238x; 1.0596x over previous
//
#include <hip/hip_runtime.h>
#include <math.h>

#define NMAT   16384
#define CHEB_A 0.08
#define CHEB_B 7.0
#define DDEG   29            // Chebyshev degree (odd); truncation tail ~5e-4 on [a,b]
#define NCOEF  (DDEG + 1)
#define NITER  ((DDEG - 1) / 2)   // Clenshaw pair-iterations
#define NLOGBLK 1024         // k_logsum blocks
#define NWAVES4 (NLOGBLK * 4) // 4096 waves; each wave owns 4 matrices (stride NWAVES4)
#define NOUTBLK 1024         // k_out blocks
#define NOUTWV  (NOUTBLK * 4)

// ws float layout
#define WS_GQ    0
#define WS_GSQ   1024
#define WS_C     2112
#define WS_CT    3136

// d_out float scratch layout (consumed before final kernel overwrites):
#define OUT_PA   0          // 256*1024  (stage-1 partial sums of X)
#define OUT_PL   262144     // 1024*1024 (stage-3 partial sums of log)
#define OUT_PL2  1310720    // 32*1024

typedef __attribute__((ext_vector_type(8)))  short short8;   // 8 bf16 (4 VGPRs)
typedef __attribute__((ext_vector_type(16))) float f32x16;   // MFMA 32x32 C/D
typedef __attribute__((ext_vector_type(2)))  float f32x2;
typedef __attribute__((ext_vector_type(2)))  __bf16 bf16x2;

union FB { short8 v; unsigned int w[4]; };

// row of C/D-layout register r for half h: (r&3) + 8*(r>>2) + 4*h
#define ROWOF(r, h) (((r) & 3) + 8 * ((r) >> 2) + 4 * (h))

// round-half-up f32->bf16, pack pair into one dword (lo=a, hi=b). Split-path
// (keeps hi/lo splits exactly consistent with rhi()).
__device__ __forceinline__ unsigned int pk2(float a, float b) {
    unsigned int au = __float_as_uint(a) + 0x8000u;
    unsigned int bu = __float_as_uint(b) + 0x8000u;
    return __builtin_amdgcn_perm(bu, au, 0x07060302u);
}
__device__ __forceinline__ float rhi(float x) {   // bf16-rounded value as float
    return __uint_as_float((__float_as_uint(x) + 0x8000u) & 0xffff0000u);
}

// hot-path pack: RNE pack of 2 f32 -> 2 bf16 (lo=a, hi=b), compiler-emitted
// (vector fptrunc; gfx950 backend selects v_cvt_pk_bf16_f32 itself).
__device__ __forceinline__ unsigned int cvt2(float a, float b) {
    f32x2 s; s.x = a; s.y = b;
    bf16x2 t = __builtin_convertvector(s, bf16x2);
    unsigned int r;
    __builtin_memcpy(&r, &t, 4);
    return r;
}

// D (C/D layout fp32) -> two B-operand k-half fragments, pure in-register.
// C/D layout is column-owned (lane holds col=lane&31, rows (r&3)+8*(r>>2)+4h);
// B layout is also column-owned (lane holds col, k=8h+e). The only data motion
// needed is a half-wave exchange lane <-> lane^32: v_permlane32_swap_b32.
template <bool HALF>
__device__ __forceinline__ void toB(const f32x16& d, FB& b1, FB& b2) {
    unsigned int p[8];
#pragma unroll
    for (int g = 0; g < 8; ++g) {
        float s0 = HALF ? 0.5f * d[2 * g]     : d[2 * g];
        float s1 = HALF ? 0.5f * d[2 * g + 1] : d[2 * g + 1];
        p[g] = cvt2(s0, s1);
    }
    auto r02 = __builtin_amdgcn_permlane32_swap(p[0], p[2], false, false);
    auto r13 = __builtin_amdgcn_permlane32_swap(p[1], p[3], false, false);
    auto r46 = __builtin_amdgcn_permlane32_swap(p[4], p[6], false, false);
    auto r57 = __builtin_amdgcn_permlane32_swap(p[5], p[7], false, false);
    b1.w[0] = r02[0]; b1.w[1] = r13[0]; b1.w[2] = r02[1]; b1.w[3] = r13[1];
    b2.w[0] = r46[0]; b2.w[1] = r57[0]; b2.w[2] = r46[1]; b2.w[3] = r57[1];
}

#define MFMA(a, b, c) __builtin_amdgcn_mfma_f32_32x32x16_bf16((a), (b), (c), 0, 0, 0)

// ---- hi/lo split fragments of a symmetric matrix in C/D layout.
struct SplitM { FB h1, h2, l1, l2; };

__device__ __forceinline__ void splitB(const f32x16& d, SplitM& s) {
    unsigned int ph[8], pl[8];
#pragma unroll
    for (int g = 0; g < 8; ++g) {
        float a = d[2 * g], b = d[2 * g + 1];
        ph[g] = pk2(a, b);
        pl[g] = pk2(a - rhi(a), b - rhi(b));
    }
    auto h02 = __builtin_amdgcn_permlane32_swap(ph[0], ph[2], false, false);
    auto h13 = __builtin_amdgcn_permlane32_swap(ph[1], ph[3], false, false);
    auto h46 = __builtin_amdgcn_permlane32_swap(ph[4], ph[6], false, false);
    auto h57 = __builtin_amdgcn_permlane32_swap(ph[5], ph[7], false, false);
    s.h1.w[0] = h02[0]; s.h1.w[1] = h13[0]; s.h1.w[2] = h02[1]; s.h1.w[3] = h13[1];
    s.h2.w[0] = h46[0]; s.h2.w[1] = h57[0]; s.h2.w[2] = h46[1]; s.h2.w[3] = h57[1];
    auto l02 = __builtin_amdgcn_permlane32_swap(pl[0], pl[2], false, false);
    auto l13 = __builtin_amdgcn_permlane32_swap(pl[1], pl[3], false, false);
    auto l46 = __builtin_amdgcn_permlane32_swap(pl[4], pl[6], false, false);
    auto l57 = __builtin_amdgcn_permlane32_swap(pl[5], pl[7], false, false);
    s.l1.w[0] = l02[0]; s.l1.w[1] = l13[0]; s.l1.w[2] = l02[1]; s.l1.w[3] = l13[1];
    s.l2.w[0] = l46[0]; s.l2.w[1] = l57[0]; s.l2.w[2] = l46[1]; s.l2.w[3] = l57[1];
}

// D = A*B for split operands. The fragment duality: a B-frag set of matrix M,
// fed as the A-operand, represents M^T. So A here must be either a symmetric
// matrix's frags, or the frags of (desired A)^T.
__device__ __forceinline__ f32x16 mulSS(const SplitM& A, const SplitM& B) {
    f32x16 d;
#pragma unroll
    for (int r = 0; r < 16; ++r) d[r] = 0.f;
    d = MFMA(A.h2.v, B.l2.v, d); d = MFMA(A.h1.v, B.l1.v, d);
    d = MFMA(A.l2.v, B.h2.v, d); d = MFMA(A.l1.v, B.h1.v, d);
    d = MFMA(A.h2.v, B.h2.v, d); d = MFMA(A.h1.v, B.h1.v, d);
    return d;
}

// build split frags directly from a row-major 32x32 global/ws tile, reading
// M[col][k] per lane (the Gq load pattern) -> B-frags of M without permlane.
__device__ __forceinline__ void loadSplit(const float* __restrict__ base,
                                          int col, int h, SplitM& s) {
    const float* p = base + col * 32 + 8 * h;
    float4 a = *(const float4*)(p);
    float4 b = *(const float4*)(p + 4);
    float4 c = *(const float4*)(p + 16);
    float4 d = *(const float4*)(p + 20);
    s.h1.w[0] = pk2(a.x, a.y); s.h1.w[1] = pk2(a.z, a.w);
    s.h1.w[2] = pk2(b.x, b.y); s.h1.w[3] = pk2(b.z, b.w);
    s.h2.w[0] = pk2(c.x, c.y); s.h2.w[1] = pk2(c.z, c.w);
    s.h2.w[2] = pk2(d.x, d.y); s.h2.w[3] = pk2(d.z, d.w);
    s.l1.w[0] = pk2(a.x - rhi(a.x), a.y - rhi(a.y));
    s.l1.w[1] = pk2(a.z - rhi(a.z), a.w - rhi(a.w));
    s.l1.w[2] = pk2(b.x - rhi(b.x), b.y - rhi(b.y));
    s.l1.w[3] = pk2(b.z - rhi(b.z), b.w - rhi(b.w));
    s.l2.w[0] = pk2(c.x - rhi(c.x), c.y - rhi(c.y));
    s.l2.w[1] = pk2(c.z - rhi(c.z), c.w - rhi(c.w));
    s.l2.w[2] = pk2(d.x - rhi(d.x), d.y - rhi(d.y));
    s.l2.w[3] = pk2(d.z - rhi(d.z), d.w - rhi(d.w));
}

__device__ __forceinline__ float wred(float v) {   // 64-lane sum, broadcast
    v += __shfl_xor(v, 32);
    v += __shfl_xor(v, 16);
    v += __shfl_xor(v, 8);
    v += __shfl_xor(v, 4);
    v += __shfl_xor(v, 2);
    v += __shfl_xor(v, 1);
    return v;
}

// ---------------- block-level 32x32 matmul on LDS (row-major), 256 threads ----------------
__device__ __forceinline__ void mm32(const float* A, const float* B, float* D, int t) {
    int i = t >> 3, j0 = (t & 7) * 4;
    float a[32];
#pragma unroll
    for (int q = 0; q < 8; ++q) {
        float4 v = *(const float4*)&A[i * 32 + q * 4];
        a[4 * q] = v.x; a[4 * q + 1] = v.y; a[4 * q + 2] = v.z; a[4 * q + 3] = v.w;
    }
    float ax = 0.f, ay = 0.f, az = 0.f, aw = 0.f;
#pragma unroll
    for (int k = 0; k < 32; ++k) {
        float4 bv = *(const float4*)&B[k * 32 + j0];
        ax += a[k] * bv.x; ay += a[k] * bv.y; az += a[k] * bv.z; aw += a[k] * bv.w;
    }
    float4 r = { ax, ay, az, aw };
    *(float4*)&D[i * 32 + j0] = r;
}

// ---------------- K1: partial sums (256 blocks x 64 matrices) ----------------
__global__ __launch_bounds__(256) void k_psum(const float4* __restrict__ X4,
                                              float4* __restrict__ pA4) {
    int b = blockIdx.x, t = threadIdx.x;
    float4 acc = { 0.f, 0.f, 0.f, 0.f };
    for (int r = 0; r < 64; ++r) {
        float4 v = X4[(size_t)(b * 64 + r) * 256 + t];
        acc.x += v.x; acc.y += v.y; acc.z += v.z; acc.w += v.w;
    }
    pA4[b * 256 + t] = acc;
}

// ---------------- K2: finalize G, G^{1/2}, G^{-1/2} ----------------
__global__ __launch_bounds__(256) void k_setup(const float4* __restrict__ pA4,
                                               float* __restrict__ ws) {
    __shared__ alignas(16) float sG[1024], sE[1024], sPa[1024], sPb[1024], sS1[1024], sS2[1024];
    __shared__ float sc[2];
    int t = threadIdx.x;
    float4 acc = { 0.f, 0.f, 0.f, 0.f };
    for (int b = 0; b < 256; ++b) {
        float4 v = pA4[b * 256 + t];
        acc.x += v.x; acc.y += v.y; acc.z += v.z; acc.w += v.w;
    }
    const float invM = 1.0f / (float)NMAT;
    sG[4 * t + 0] = acc.x * invM; sG[4 * t + 1] = acc.y * invM;
    sG[4 * t + 2] = acc.z * invM; sG[4 * t + 3] = acc.w * invM;
    __syncthreads();
    if (t == 0) { float s = 0.f; for (int d = 0; d < 32; ++d) s += sG[d * 33]; sc[0] = s / 32.0f; }
    __syncthreads();
    float c = sc[0];
    int i = t >> 3, j0 = (t & 7) * 4;
#pragma unroll
    for (int q = 0; q < 4; ++q) {
        int e = i * 32 + j0 + q;
        sE[e] = sG[e] / c - ((i == j0 + q) ? 1.f : 0.f);
    }
    __syncthreads();
    const float alp[9] = { 1.f, 0.5f, -0.125f, 0.0625f, -0.0390625f, 0.02734375f,
                           -0.0205078125f, 0.01611328125f, -0.013092041015625f };
    const float bet[9] = { 1.f, -0.5f, 0.375f, -0.3125f, 0.2734375f, -0.24609375f,
                           0.2255859375f, -0.20947265625f, 0.196380615234375f };
#pragma unroll
    for (int q = 0; q < 4; ++q) {
        int e = i * 32 + j0 + q;
        float d = (i == j0 + q) ? 1.f : 0.f;
        sS1[e] = d + alp[1] * sE[e];
        sS2[e] = d + bet[1] * sE[e];
        sPa[e] = sE[e];
    }
    __syncthreads();
    {
        float* P = sPa; float* Pn = sPb;
        for (int k = 2; k <= 8; ++k) {
            mm32(P, sE, Pn, t);
            __syncthreads();
#pragma unroll
            for (int q = 0; q < 4; ++q) {
                int e = i * 32 + j0 + q;
                sS1[e] += alp[k] * Pn[e];
                sS2[e] += bet[k] * Pn[e];
            }
            float* tmp = P; P = Pn; Pn = tmp;
            __syncthreads();
        }
    }
    float rc = sqrtf(c);
#pragma unroll
    for (int q = 0; q < 4; ++q) {
        int e = i * 32 + j0 + q;
        ws[WS_GSQ + e] = rc * sS1[e];
        ws[WS_GQ + e]  = sS2[e] / rc;
    }
}

// ---------------- K3: sum of matrix logs, quad-chain MFMA Clenshaw ----------------
// Each wave owns 4 matrices (stride NWAVES4) and runs all four Clenshaw chains
// concurrently: 4 independent dependency chains fill MFMA/VALU latency.
// Register budget: 4 x (X0,X1 32 + A 8 + B 8) = 192 + dm 16 + scalars (~230).
// Spill tripwire: WRITE_SIZE ballooning past ~8 MB.
__global__ __launch_bounds__(256, 2) void k_logsum(const float* __restrict__ Xg,
                                                   const float* __restrict__ ws,
                                                   float* __restrict__ pL) {
    __shared__ float sLacc[1024];
    __shared__ float scheb[NCOEF];
    int t = threadIdx.x;
    for (int e = t; e < 1024; e += 256) sLacc[e] = 0.f;
    if (t < NCOEF) {
        // closed-form Chebyshev coeffs of log on [a,b]
        float alpha = 0.5f * (float)(CHEB_A + CHEB_B);
        float beta  = 0.5f * (float)(CHEB_B - CHEB_A);
        float dd = beta / alpha, s = sqrtf(1.f - dd * dd), tt = dd / (1.f + s);
        float v;
        if (t == 0) v = 2.f * (logf(alpha) + logf(0.5f * (1.f + s)));
        else        v = 2.f * ((t & 1) ? 1.f : -1.f) * exp2f((float)t * log2f(tt)) / (float)t;
        scheb[t] = v;
    }
    const int wv = t >> 6, lane = t & 63, h = lane >> 5, col = lane & 31;

    // diagonal mask in C/D layout: row(reg)=(reg&3)+8*(reg>>2)+4h == col
    int hasd = (((col >> 2) & 1) == h);
    int dreg = 4 * (col >> 3) + (col & 3);
    f32x16 dm;
#pragma unroll
    for (int r = 0; r < 16; ++r) dm[r] = (hasd && r == dreg) ? 1.f : 0.f;

    // Gq fragments (symmetric; same regs serve as A- and B-operand), hi/lo split
    FB GqH1, GqH2, GqL1, GqL2;
    {
        SplitM SGq;
        loadSplit(ws + WS_GQ, col, h, SGq);
        GqH1 = SGq.h1; GqH2 = SGq.h2; GqL1 = SGq.l1; GqL2 = SGq.l2;
    }
    __syncthreads();   // scheb + sLacc ready

    const float m2v = 2.0f / (float)(CHEB_B - CHEB_A);
    const float shv = (float)((CHEB_A + CHEB_B) / (CHEB_B - CHEB_A));
    const float tm = 2.f * m2v, tsh = -2.f * shv;
    const float cDv = scheb[DDEG], c0h = 0.5f * scheb[0];

    const int m0 = blockIdx.x * 4 + wv;

    // ---- load + pack all four matrices
    const float* Xma = Xg + (size_t)(m0)                * 1024 + col * 32 + 8 * h;
    const float* Xmb = Xg + (size_t)(m0 + NWAVES4)      * 1024 + col * 32 + 8 * h;
    const float* Xmc = Xg + (size_t)(m0 + 2 * NWAVES4)  * 1024 + col * 32 + 8 * h;
    const float* Xmd = Xg + (size_t)(m0 + 3 * NWAVES4)  * 1024 + col * 32 + 8 * h;
    FB AXa1, AXa2, AXb1, AXb2, AXc1, AXc2, AXd1, AXd2;
    {
        float4 v0 = *(const float4*)(Xma);
        float4 v1 = *(const float4*)(Xma + 4);
        float4 v2 = *(const float4*)(Xma + 16);
        float4 v3 = *(const float4*)(Xma + 20);
        AXa1.w[0] = cvt2(v0.x, v0.y); AXa1.w[1] = cvt2(v0.z, v0.w);
        AXa1.w[2] = cvt2(v1.x, v1.y); AXa1.w[3] = cvt2(v1.z, v1.w);
        AXa2.w[0] = cvt2(v2.x, v2.y); AXa2.w[1] = cvt2(v2.z, v2.w);
        AXa2.w[2] = cvt2(v3.x, v3.y); AXa2.w[3] = cvt2(v3.z, v3.w);
    }
    {
        float4 v0 = *(const float4*)(Xmb);
        float4 v1 = *(const float4*)(Xmb + 4);
        float4 v2 = *(const float4*)(Xmb + 16);
        float4 v3 = *(const float4*)(Xmb + 20);
        AXb1.w[0] = cvt2(v0.x, v0.y); AXb1.w[1] = cvt2(v0.z, v0.w);
        AXb1.w[2] = cvt2(v1.x, v1.y); AXb1.w[3] = cvt2(v1.z, v1.w);
        AXb2.w[0] = cvt2(v2.x, v2.y); AXb2.w[1] = cvt2(v2.z, v2.w);
        AXb2.w[2] = cvt2(v3.x, v3.y); AXb2.w[3] = cvt2(v3.z, v3.w);
    }
    {
        float4 v0 = *(const float4*)(Xmc);
        float4 v1 = *(const float4*)(Xmc + 4);
        float4 v2 = *(const float4*)(Xmc + 16);
        float4 v3 = *(const float4*)(Xmc + 20);
        AXc1.w[0] = cvt2(v0.x, v0.y); AXc1.w[1] = cvt2(v0.z, v0.w);
        AXc1.w[2] = cvt2(v1.x, v1.y); AXc1.w[3] = cvt2(v1.z, v1.w);
        AXc2.w[0] = cvt2(v2.x, v2.y); AXc2.w[1] = cvt2(v2.z, v2.w);
        AXc2.w[2] = cvt2(v3.x, v3.y); AXc2.w[3] = cvt2(v3.z, v3.w);
    }
    {
        float4 v0 = *(const float4*)(Xmd);
        float4 v1 = *(const float4*)(Xmd + 4);
        float4 v2 = *(const float4*)(Xmd + 16);
        float4 v3 = *(const float4*)(Xmd + 20);
        AXd1.w[0] = cvt2(v0.x, v0.y); AXd1.w[1] = cvt2(v0.z, v0.w);
        AXd1.w[2] = cvt2(v1.x, v1.y); AXd1.w[3] = cvt2(v1.z, v1.w);
        AXd2.w[0] = cvt2(v2.x, v2.y); AXd2.w[1] = cvt2(v2.z, v2.w);
        AXd2.w[2] = cvt2(v3.x, v3.y); AXd2.w[3] = cvt2(v3.z, v3.w);
    }

    // ---- U = X * Gq (all chains)
    f32x16 Ua, Ub, Uc, Ud;
#pragma unroll
    for (int r = 0; r < 16; ++r) { Ua[r] = 0.f; Ub[r] = 0.f; Uc[r] = 0.f; Ud[r] = 0.f; }
    Ua = MFMA(AXa2.v, GqL2.v, Ua); Ub = MFMA(AXb2.v, GqL2.v, Ub);
    Uc = MFMA(AXc2.v, GqL2.v, Uc); Ud = MFMA(AXd2.v, GqL2.v, Ud);
    Ua = MFMA(AXa1.v, GqL1.v, Ua); Ub = MFMA(AXb1.v, GqL1.v, Ub);
    Uc = MFMA(AXc1.v, GqL1.v, Uc); Ud = MFMA(AXd1.v, GqL1.v, Ud);
    Ua = MFMA(AXa2.v, GqH2.v, Ua); Ub = MFMA(AXb2.v, GqH2.v, Ub);
    Uc = MFMA(AXc2.v, GqH2.v, Uc); Ud = MFMA(AXd2.v, GqH2.v, Ud);
    Ua = MFMA(AXa1.v, GqH1.v, Ua); Ub = MFMA(AXb1.v, GqH1.v, Ub);
    Uc = MFMA(AXc1.v, GqH1.v, Uc); Ud = MFMA(AXd1.v, GqH1.v, Ud);
    FB Ba1, Ba2, Bb1, Bb2, Bc1, Bc2, Bd1, Bd2;
    toB<false>(Ua, Ba1, Ba2); toB<false>(Ub, Bb1, Bb2);
    toB<false>(Uc, Bc1, Bc2); toB<false>(Ud, Bd1, Bd2);
    // ---- S = Gq * U
    f32x16 Sa, Sb, Sc, Sd;
#pragma unroll
    for (int r = 0; r < 16; ++r) { Sa[r] = 0.f; Sb[r] = 0.f; Sc[r] = 0.f; Sd[r] = 0.f; }
    Sa = MFMA(GqL2.v, Ba2.v, Sa); Sb = MFMA(GqL2.v, Bb2.v, Sb);
    Sc = MFMA(GqL2.v, Bc2.v, Sc); Sd = MFMA(GqL2.v, Bd2.v, Sd);
    Sa = MFMA(GqL1.v, Ba1.v, Sa); Sb = MFMA(GqL1.v, Bb1.v, Sb);
    Sc = MFMA(GqL1.v, Bc1.v, Sc); Sd = MFMA(GqL1.v, Bd1.v, Sd);
    Sa = MFMA(GqH2.v, Ba2.v, Sa); Sb = MFMA(GqH2.v, Bb2.v, Sb);
    Sc = MFMA(GqH2.v, Bc2.v, Sc); Sd = MFMA(GqH2.v, Bd2.v, Sd);
    Sa = MFMA(GqH1.v, Ba1.v, Sa); Sb = MFMA(GqH1.v, Bb1.v, Sb);
    Sc = MFMA(GqH1.v, Bc1.v, Sc); Sd = MFMA(GqH1.v, Bd1.v, Sd);
    // ---- 2*Shat = tm*S + tsh*I -> A-operand frags (symmetric)
    FB Aa1, Aa2, Ab1, Ab2, Ac1, Ac2, Ad1, Ad2;
    {
        f32x16 Ta, Tb, Tc, Td;
#pragma unroll
        for (int r = 0; r < 16; ++r) {
            Ta[r] = fmaf(tm, Sa[r], tsh * dm[r]);
            Tb[r] = fmaf(tm, Sb[r], tsh * dm[r]);
            Tc[r] = fmaf(tm, Sc[r], tsh * dm[r]);
            Td[r] = fmaf(tm, Sd[r], tsh * dm[r]);
        }
        toB<false>(Ta, Aa1, Aa2); toB<false>(Tb, Ab1, Ab2);
        toB<false>(Tc, Ac1, Ac2); toB<false>(Td, Ad1, Ad2);
    }

    // ---- Clenshaw: b_k = c_k I - b_{k+2} + (2Shat)*b_{k+1}, all chains
    f32x16 X0a, X1a, X0b, X1b, X0c, X1c, X0d, X1d;
#pragma unroll
    for (int r = 0; r < 16; ++r) {
        float cd = cDv * dm[r];
        X1a[r] = cd; X0a[r] = 0.f;
        X1b[r] = cd; X0b[r] = 0.f;
        X1c[r] = cd; X0c[r] = 0.f;
        X1d[r] = cd; X0d[r] = 0.f;
    }
    toB<false>(X1a, Ba1, Ba2);       // seed frags of cD*I (shared)
    Bb1 = Ba1; Bb2 = Ba2; Bc1 = Ba1; Bc2 = Ba2; Bd1 = Ba1; Bd2 = Ba2;
    for (int it = 0; it < NITER; ++it) {
        float ka = scheb[DDEG - 1 - 2 * it];
        float kb = scheb[DDEG - 2 - 2 * it];
#pragma unroll
        for (int r = 0; r < 16; ++r) {
            float kd = ka * dm[r];
            X0a[r] = kd - X0a[r];
            X0b[r] = kd - X0b[r];
            X0c[r] = kd - X0c[r];
            X0d[r] = kd - X0d[r];
        }
        X0a = MFMA(Aa2.v, Ba2.v, X0a); X0b = MFMA(Ab2.v, Bb2.v, X0b);
        X0c = MFMA(Ac2.v, Bc2.v, X0c); X0d = MFMA(Ad2.v, Bd2.v, X0d);
        X0a = MFMA(Aa1.v, Ba1.v, X0a); X0b = MFMA(Ab1.v, Bb1.v, X0b);
        X0c = MFMA(Ac1.v, Bc1.v, X0c); X0d = MFMA(Ad1.v, Bd1.v, X0d);
        toB<false>(X0a, Ba1, Ba2); toB<false>(X0b, Bb1, Bb2);
        toB<false>(X0c, Bc1, Bc2); toB<false>(X0d, Bd1, Bd2);
#pragma unroll
        for (int r = 0; r < 16; ++r) {
            float kd = kb * dm[r];
            X1a[r] = kd - X1a[r];
            X1b[r] = kd - X1b[r];
            X1c[r] = kd - X1c[r];
            X1d[r] = kd - X1d[r];
        }
        X1a = MFMA(Aa2.v, Ba2.v, X1a); X1b = MFMA(Ab2.v, Bb2.v, X1b);
        X1c = MFMA(Ac2.v, Bc2.v, X1c); X1d = MFMA(Ad2.v, Bd2.v, X1d);
        X1a = MFMA(Aa1.v, Ba1.v, X1a); X1b = MFMA(Ab1.v, Bb1.v, X1b);
        X1c = MFMA(Ac1.v, Bc1.v, X1c); X1d = MFMA(Ad1.v, Bd1.v, X1d);
        if (it < NITER - 1) {
            toB<false>(X1a, Ba1, Ba2); toB<false>(X1b, Bb1, Bb2);
            toB<false>(X1c, Bc1, Bc2); toB<false>(X1d, Bd1, Bd2);
        } else {
            toB<true>(X1a, Ba1, Ba2); toB<true>(X1b, Bb1, Bb2);   // 0.5*b_1
            toB<true>(X1c, Bc1, Bc2); toB<true>(X1d, Bd1, Bd2);
        }
    }
    // ---- f = 0.5*c0 I - b_2 + (2Shat)*(0.5 b_1)
#pragma unroll
    for (int r = 0; r < 16; ++r) {
        float kd = c0h * dm[r];
        X0a[r] = kd - X0a[r];
        X0b[r] = kd - X0b[r];
        X0c[r] = kd - X0c[r];
        X0d[r] = kd - X0d[r];
    }
    X0a = MFMA(Aa2.v, Ba2.v, X0a); X0b = MFMA(Ab2.v, Bb2.v, X0b);
    X0c = MFMA(Ac2.v, Bc2.v, X0c); X0d = MFMA(Ad2.v, Bd2.v, X0d);
    X0a = MFMA(Aa1.v, Ba1.v, X0a); X0b = MFMA(Ab1.v, Bb1.v, X0b);
    X0c = MFMA(Ac1.v, Bc1.v, X0c); X0d = MFMA(Ad1.v, Bd1.v, X0d);

    f32x16 Facc;
#pragma unroll
    for (int r = 0; r < 16; ++r) Facc[r] = (X0a[r] + X0b[r]) + (X0c[r] + X0d[r]);

#pragma unroll
    for (int r = 0; r < 16; ++r) {
        int row = (r & 3) + 8 * (r >> 2) + 4 * h;
        atomicAdd(&sLacc[row * 32 + col], Facc[r]);
    }
    __syncthreads();
    float4 v = *(float4*)&sLacc[4 * t];
    ((float4*)pL)[(size_t)blockIdx.x * 256 + t] = v;
}

// ---------------- K3b: reduce 1024 partials -> 32 ----------------
__global__ __launch_bounds__(256) void k_red32(const float4* __restrict__ pL4,
                                               float4* __restrict__ pL24) {
    int b = blockIdx.x, t = threadIdx.x;
    float4 acc = { 0.f, 0.f, 0.f, 0.f };
    for (int r = 0; r < 32; ++r) {
        float4 v = pL4[(size_t)(b * 32 + r) * 256 + t];
        acc.x += v.x; acc.y += v.y; acc.z += v.z; acc.w += v.w;
    }
    pL24[b * 256 + t] = acc;
}

// ---------------- K4: single-wave MFMA chain: L -> expL -> Gn -> Gn^{-1/2};
//                  W^{1/2}; C = Wsq*Gn_isq. ----------------
__global__ __launch_bounds__(256) void k_final(const float4* __restrict__ pL24,
                                               const float* __restrict__ Wg,
                                               float* __restrict__ ws) {
    __shared__ alignas(16) float sL[1024];
    int t = threadIdx.x;
    // stage: all 256 threads reduce the 32 partials
    {
        float4 acc = { 0.f, 0.f, 0.f, 0.f };
        for (int b = 0; b < 32; ++b) {
            float4 v = pL24[b * 256 + t];
            acc.x += v.x; acc.y += v.y; acc.z += v.z; acc.w += v.w;
        }
        const float invM = 1.0f / (float)NMAT;
        sL[4 * t + 0] = acc.x * invM; sL[4 * t + 1] = acc.y * invM;
        sL[4 * t + 2] = acc.z * invM; sL[4 * t + 3] = acc.w * invM;
    }
    __syncthreads();
    if (t >= 64) return;          // wave 0 only from here (no more barriers)

    const int h = t >> 5, col = t & 31;
    const int hasd = (((col >> 2) & 1) == h);
    const int dreg = 4 * (col >> 3) + (col & 3);
    f32x16 dm;
#pragma unroll
    for (int r = 0; r < 16; ++r) dm[r] = (hasd && r == dreg) ? 1.f : 0.f;

    // mean-L into C/D registers
    f32x16 Lm;
#pragma unroll
    for (int r = 0; r < 16; ++r) Lm[r] = sL[ROWOF(r, h) * 32 + col];

    // s0 = tr(L)/32
    float tr = 0.f;
#pragma unroll
    for (int r = 0; r < 16; ++r) tr = fmaf(Lm[r], dm[r], tr);
    float s0 = wred(tr) / 32.0f;

    f32x16 L0;
#pragma unroll
    for (int r = 0; r < 16; ++r) L0[r] = fmaf(-s0, dm[r], Lm[r]);

    // expm series: E4 = sum_{k=0}^{12} L0^k/k!
    SplitM SL0; splitB(L0, SL0);
    f32x16 E4;
#pragma unroll
    for (int r = 0; r < 16; ++r) E4[r] = dm[r] + L0[r];
    SplitM SP = SL0;
    for (int k = 2; k <= 12; ++k) {
        f32x16 Pn = mulSS(SP, SL0);        // P * L0 (A=P symmetric)
        float invk = 1.0f / (float)k;
#pragma unroll
        for (int r = 0; r < 16; ++r) { Pn[r] *= invk; E4[r] += Pn[r]; }
        if (k < 12) splitB(Pn, SP);
    }
    float es = expf(s0);
#pragma unroll
    for (int r = 0; r < 16; ++r) E4[r] *= es;   // expL

    // Gn = Gsq * (expL * Gsq)
    f32x16 Gs;
#pragma unroll
    for (int r = 0; r < 16; ++r) Gs[r] = ws[WS_GSQ + ROWOF(r, h) * 32 + col];
    SplitM SG; splitB(Gs, SG);
    SplitM SE; splitB(E4, SE);
    f32x16 Mx = mulSS(SE, SG);              // expL*Gsq (A=expL sym; Mx NOT sym)
    SplitM SM; splitB(Mx, SM);
    f32x16 Gn = mulSS(SG, SM);              // A=Gsq sym, B=Mx

    // c2 = tr(Gn)/32; coupled NS x8 for (Gn/c2)^{-1/2}
    float tr2 = 0.f;
#pragma unroll
    for (int r = 0; r < 16; ++r) tr2 = fmaf(Gn[r], dm[r], tr2);
    float c2 = wred(tr2) / 32.0f;
    float ic2 = 1.0f / c2;

    f32x16 YC, ZC;
#pragma unroll
    for (int r = 0; r < 16; ++r) { YC[r] = Gn[r] * ic2; ZC[r] = dm[r]; }
    SplitM SY, SZ, ST;
    splitB(YC, SY); splitB(ZC, SZ);
    for (int it = 0; it < 8; ++it) {
        f32x16 ZY = mulSS(SZ, SY);          // Z*Y (Z sym)
        f32x16 T;
#pragma unroll
        for (int r = 0; r < 16; ++r) T[r] = fmaf(1.5f, dm[r], -0.5f * ZY[r]);
        splitB(T, ST);
        f32x16 Yn = mulSS(SY, ST);          // Y*T (Y sym)
        f32x16 Zn = mulSS(ST, SZ);          // T*Z (T sym)
        YC = Yn; ZC = Zn;
        splitB(YC, SY); splitB(ZC, SZ);
    }
    float rc2 = rsqrtf(c2);
    f32x16 Gi;
#pragma unroll
    for (int r = 0; r < 16; ++r) Gi[r] = ZC[r] * rc2;   // Gn^{-1/2}
    SplitM SGi; splitB(Gi, SGi);

    // W^{1/2}: c3 = ||W||_F; NS x15
    f32x16 Wm;
#pragma unroll
    for (int r = 0; r < 16; ++r) Wm[r] = Wg[ROWOF(r, h) * 32 + col];
    float ss = 0.f;
#pragma unroll
    for (int r = 0; r < 16; ++r) ss = fmaf(Wm[r], Wm[r], ss);
    float c3 = sqrtf(wred(ss));
    float ic3 = 1.0f / c3;
#pragma unroll
    for (int r = 0; r < 16; ++r) { YC[r] = Wm[r] * ic3; ZC[r] = dm[r]; }
    splitB(YC, SY); splitB(ZC, SZ);
    for (int it = 0; it < 15; ++it) {
        f32x16 ZY = mulSS(SZ, SY);
        f32x16 T;
#pragma unroll
        for (int r = 0; r < 16; ++r) T[r] = fmaf(1.5f, dm[r], -0.5f * ZY[r]);
        splitB(T, ST);
        f32x16 Yn = mulSS(SY, ST);
        f32x16 Zn = mulSS(ST, SZ);
        YC = Yn; ZC = Zn;
        splitB(YC, SY); splitB(ZC, SZ);
    }
    float rc3 = sqrtf(c3);
    f32x16 Ws;
#pragma unroll
    for (int r = 0; r < 16; ++r) Ws[r] = YC[r] * rc3;   // W^{1/2}
    SplitM SW; splitB(Ws, SW);

    f32x16 C = mulSS(SW, SGi);              // C = Wsq * Gn_isq (Wsq sym)
#pragma unroll
    for (int r = 0; r < 16; ++r) {
        int row = ROWOF(r, h);
        ws[WS_C + row * 32 + col] = C[r];
        ws[WS_CT + col * 32 + row] = C[r];
    }
}

// ---------------- K5: out = C * X * C^T via MFMA ----------------
// Fragment duality: B-frags of C^T (direct-loaded from WS_C: C^T[k][col] =
// C[col][k] = ws[WS_C + col*32 + k]) serve as (a) the B-operand for V = X*C^T
// and (b) the A-operand for out = C*V. X and V hi/lo-split (3-term products).
__global__ __launch_bounds__(256) void k_out(const float* __restrict__ Xg,
                                             const float* __restrict__ ws,
                                             float* __restrict__ Og) {
    int t = threadIdx.x;
    const int wv = t >> 6, lane = t & 63, h = lane >> 5, col = lane & 31;
    SplitM SCt;
    loadSplit(ws + WS_C, col, h, SCt);   // frags of C^T (constant per wave)

    for (int m = blockIdx.x * 4 + wv; m < NMAT; m += NOUTWV) {
        SplitM SX;
        loadSplit(Xg + (size_t)m * 1024, col, h, SX);   // frags of X (sym)
        f32x16 V = mulSS(SX, SCt);        // V = X * C^T  (A = X, symmetric)
        SplitM SV; splitB(V, SV);
        f32x16 O = mulSS(SCt, SV);        // out = C * V  (A-frags of C = SCt)
        float* Om = Og + (size_t)m * 1024;
#pragma unroll
        for (int r = 0; r < 16; ++r) {
            Om[ROWOF(r, h) * 32 + col] = O[r];
        }
    }
}

extern "C" void kernel_launch(void* const* d_in, const int* in_sizes, int n_in,
                              void* d_out, int out_size, void* d_ws, size_t ws_size,
                              hipStream_t stream) {
    const float* X = (const float*)d_in[0];
    const float* W = (const float*)d_in[1];
    float* out = (float*)d_out;
    float* ws  = (float*)d_ws;
    float* pA  = out + OUT_PA;
    float* pL  = out + OUT_PL;
    float* pL2 = out + OUT_PL2;

    hipLaunchKernelGGL(k_psum,   dim3(256),     dim3(256), 0, stream, (const float4*)X, (float4*)pA);
    hipLaunchKernelGGL(k_setup,  dim3(1),       dim3(256), 0, stream, (const float4*)pA, ws);
    hipLaunchKernelGGL(k_logsum, dim3(NLOGBLK), dim3(256), 0, stream, X, ws, pL);
    hipLaunchKernelGGL(k_red32,  dim3(32),      dim3(256), 0, stream, (const float4*)pL, (float4*)pL2);
    hipLaunchKernelGGL(k_final,  dim3(1),       dim3(256), 0, stream, (const float4*)pL2, W, ws);
    hipLaunchKernelGGL(k_out,    dim3(NOUTBLK), dim3(256), 0, stream, X, ws, out);
}